// Round 4
// baseline (5894.703 us; speedup 1.0000x reference)
//
#include <hip/hip_runtime.h>

#define EMB 64
#define BSHIFT 7                      // 128 rows per bucket
#define BROWS (1 << BSHIFT)

// ---------------------------------------------------------------------------
// ego = concat(user_emb, item_emb); also write into all_e[:, 0:64]
// ---------------------------------------------------------------------------
__global__ void k_init_ego(const float* __restrict__ user_emb,
                           const float* __restrict__ item_emb,
                           float* __restrict__ ego, float* __restrict__ all_e,
                           int n_user, int N) {
    int idx = blockIdx.x * blockDim.x + threadIdx.x;
    int total = N * EMB;
    if (idx >= total) return;
    int n = idx >> 6;
    int c = idx & 63;
    float v = (n < n_user) ? user_emb[idx] : item_emb[(size_t)(n - n_user) * EMB + c];
    ego[idx] = v;
    all_e[(size_t)n * 256 + c] = v;
}

// ---------------------------------------------------------------------------
// Bucket histogram: bins[b] = #edges with dst>>BSHIFT == b  (LDS sub-hist)
// ---------------------------------------------------------------------------
__global__ __launch_bounds__(256) void k_bhist(const int* __restrict__ dst,
                                               int* __restrict__ bins,
                                               int M, int nbuckets) {
    __shared__ int h[2048];
    for (int i = threadIdx.x; i < nbuckets; i += 256) h[i] = 0;
    __syncthreads();
    for (int e = blockIdx.x * 256 + threadIdx.x; e < M; e += gridDim.x * 256)
        atomicAdd(&h[dst[e] >> BSHIFT], 1);
    __syncthreads();
    for (int i = threadIdx.x; i < nbuckets; i += 256)
        if (h[i]) atomicAdd(&bins[i], h[i]);
}

// ---------------------------------------------------------------------------
// Exclusive scan of nbuckets bins -> off[0..P], cursor copy (single block)
// ---------------------------------------------------------------------------
__global__ __launch_bounds__(1024) void k_bscan(const int* __restrict__ bins,
                                                int* __restrict__ off,
                                                int* __restrict__ cursor, int P) {
    __shared__ int part[1024];
    int tid = threadIdx.x;
    int chunk = (P + 1023) / 1024;
    int lo = tid * chunk, hi = min(lo + chunk, P);
    int s = 0;
    for (int i = lo; i < hi; i++) s += bins[i];
    part[tid] = s;
    __syncthreads();
    for (int d = 1; d < 1024; d <<= 1) {
        int add = (tid >= d) ? part[tid - d] : 0;
        __syncthreads();
        part[tid] += add;
        __syncthreads();
    }
    int o = part[tid] - s;
    for (int i = lo; i < hi; i++) {
        off[i] = o;
        cursor[i] = o;
        o += bins[i];
    }
    if (tid == 1023) off[P] = o;
}

// ---------------------------------------------------------------------------
// Bucket fill: entries[pos] = (src<<7 | dst&127, bits(w)); 1172 append streams
// keep tail lines hot -> near-ideal write traffic (vs full scatter thrash)
// ---------------------------------------------------------------------------
__global__ void k_bfill(const int* __restrict__ src, const int* __restrict__ dst,
                        const float* __restrict__ w, int* __restrict__ cursor,
                        int2* __restrict__ entries, int M) {
    int e = blockIdx.x * 256 + threadIdx.x;
    if (e >= M) return;
    int d = dst[e];
    int pos = atomicAdd(&cursor[d >> BSHIFT], 1);
    entries[pos] = make_int2((src[e] << BSHIFT) | (d & (BROWS - 1)),
                             __float_as_int(w[e]));
}

// ---------------------------------------------------------------------------
// side for one bucket: LDS accumulator of 128 rows x 64 f32 (32 KB).
// Wave-per-entry-chunk: gather ego row (lane=component), ds_add_f32 into acc.
// Bank = lane%32 for every row -> 2-way aliasing only (free). One streaming
// write of the bucket's side rows at the end. No global atomics.
// ---------------------------------------------------------------------------
__global__ __launch_bounds__(256) void k_side_lds(
        const int* __restrict__ off, const int2* __restrict__ entries,
        const float* __restrict__ ego, float* __restrict__ side, int N) {
    __shared__ float acc[BROWS * EMB];
    int b = blockIdx.x;
    int row0 = b << BSHIFT;
    int nrows = min(BROWS, N - row0);

    float4* a4 = (float4*)acc;
    for (int i = threadIdx.x; i < BROWS * (EMB / 4); i += 256)
        a4[i] = make_float4(0.f, 0.f, 0.f, 0.f);
    __syncthreads();

    int beg = off[b], end = off[b + 1];
    int cnt = end - beg;
    int wave = threadIdx.x >> 6, lane = threadIdx.x & 63;
    int per = (cnt + 3) >> 2;
    int e = beg + wave * per;
    int e_end = min(e + per, end);

    for (; e + 8 <= e_end; e += 8) {
        int2 m[8];
        float v[8];
#pragma unroll
        for (int j = 0; j < 8; j++) m[j] = entries[e + j];
#pragma unroll
        for (int j = 0; j < 8; j++)
            v[j] = ego[(size_t)(m[j].x >> BSHIFT) * EMB + lane];
#pragma unroll
        for (int j = 0; j < 8; j++)
            atomicAdd(&acc[((m[j].x & (BROWS - 1)) << 6) + lane],
                      __int_as_float(m[j].y) * v[j]);
    }
    for (; e < e_end; e++) {
        int2 m = entries[e];
        float v = ego[(size_t)(m.x >> BSHIFT) * EMB + lane];
        atomicAdd(&acc[((m.x & (BROWS - 1)) << 6) + lane],
                  __int_as_float(m.y) * v);
    }
    __syncthreads();

    float4* s4 = (float4*)(side + (size_t)row0 * EMB);
    int tot = nrows * (EMB / 4);
    for (int i = threadIdx.x; i < tot; i += 256) s4[i] = a4[i];
}

// ---------------------------------------------------------------------------
// Fused transform: out = leaky_relu(side@Wgc + bgc + (ego*side)@Wbi + bbi)
// ego <- out (in place); all_e[:,col] <- out/||out||.
// Thread = 4 rows x 16 cols; W broadcast from LDS; X from global as float4.
// ---------------------------------------------------------------------------
__global__ __launch_bounds__(256) void k_transform(
        const float* __restrict__ side, float* __restrict__ ego,
        const float* __restrict__ Wgc, const float* __restrict__ bgc,
        const float* __restrict__ Wbi, const float* __restrict__ bbi,
        float* __restrict__ all_e, int N, int layer_col) {
    __shared__ float sW[128][64];   // rows 0-63: Wgc, rows 64-127: Wbi
    __shared__ float sB[64];
    int tid = threadIdx.x;
    for (int i = tid; i < 64 * 64; i += 256) {
        sW[i >> 6][i & 63] = Wgc[i];
        sW[64 + (i >> 6)][i & 63] = Wbi[i];
    }
    if (tid < 64) sB[tid] = bgc[tid] + bbi[tid];
    __syncthreads();

    int cg = tid & 3;
    int rg = tid >> 2;
    int c0 = cg * 16;
    int r0 = blockIdx.x * 256 + rg * 4;

    float acc[4][16];
#pragma unroll
    for (int rr = 0; rr < 4; rr++)
#pragma unroll
        for (int c = 0; c < 16; c++) acc[rr][c] = sB[c0 + c];

    int ri[4];
#pragma unroll
    for (int rr = 0; rr < 4; rr++) ri[rr] = min(r0 + rr, N - 1);

    const float4* side4 = (const float4*)side;
    const float4* ego4 = (const float4*)ego;

#pragma unroll 1
    for (int kq = 0; kq < 16; kq++) {
        float4 x[4];
#pragma unroll
        for (int rr = 0; rr < 4; rr++) x[rr] = side4[(size_t)ri[rr] * 16 + kq];
#pragma unroll
        for (int kk = 0; kk < 4; kk++) {
            int k = kq * 4 + kk;
#pragma unroll
            for (int cq = 0; cq < 4; cq++) {
                float4 w = *(const float4*)&sW[k][c0 + cq * 4];
#pragma unroll
                for (int rr = 0; rr < 4; rr++) {
                    float xv = (&x[rr].x)[kk];
                    acc[rr][cq * 4 + 0] += xv * w.x;
                    acc[rr][cq * 4 + 1] += xv * w.y;
                    acc[rr][cq * 4 + 2] += xv * w.z;
                    acc[rr][cq * 4 + 3] += xv * w.w;
                }
            }
        }
    }

#pragma unroll 1
    for (int kq = 0; kq < 16; kq++) {
        float4 x[4];
#pragma unroll
        for (int rr = 0; rr < 4; rr++) {
            float4 a = ego4[(size_t)ri[rr] * 16 + kq];
            float4 b = side4[(size_t)ri[rr] * 16 + kq];
            x[rr] = make_float4(a.x * b.x, a.y * b.y, a.z * b.z, a.w * b.w);
        }
#pragma unroll
        for (int kk = 0; kk < 4; kk++) {
            int k = 64 + kq * 4 + kk;
#pragma unroll
            for (int cq = 0; cq < 4; cq++) {
                float4 w = *(const float4*)&sW[k][c0 + cq * 4];
#pragma unroll
                for (int rr = 0; rr < 4; rr++) {
                    float xv = (&x[rr].x)[kk];
                    acc[rr][cq * 4 + 0] += xv * w.x;
                    acc[rr][cq * 4 + 1] += xv * w.y;
                    acc[rr][cq * 4 + 2] += xv * w.z;
                    acc[rr][cq * 4 + 3] += xv * w.w;
                }
            }
        }
    }

#pragma unroll
    for (int rr = 0; rr < 4; rr++) {
        float s = 0.f;
#pragma unroll
        for (int c = 0; c < 16; c++) {
            float v = acc[rr][c];
            v = v > 0.f ? v : 0.2f * v;
            acc[rr][c] = v;
            s += v * v;
        }
        s += __shfl_xor(s, 1, 64);
        s += __shfl_xor(s, 2, 64);
        float inv = 1.0f / fmaxf(sqrtf(s), 1e-12f);
        int row = r0 + rr;
        if (row < N) {
            float4* pe = (float4*)&ego[(size_t)row * EMB + c0];
            float4* pa = (float4*)&all_e[(size_t)row * 256 + layer_col + c0];
#pragma unroll
            for (int cq = 0; cq < 4; cq++) {
                float4 v = make_float4(acc[rr][cq * 4 + 0], acc[rr][cq * 4 + 1],
                                       acc[rr][cq * 4 + 2], acc[rr][cq * 4 + 3]);
                pe[cq] = v;
                pa[cq] = make_float4(v.x * inv, v.y * inv, v.z * inv, v.w * inv);
            }
        }
    }
}

// ---------------------------------------------------------------------------
// out = [all_e[users], all_e[n_user+pos], all_e[n_user+neg]]  (each B x 256)
// ---------------------------------------------------------------------------
__global__ void k_gather(const float* __restrict__ all_e,
                         const int* __restrict__ users,
                         const int* __restrict__ pos,
                         const int* __restrict__ neg,
                         float* __restrict__ out, int n_user, int batch) {
    int idx = blockIdx.x * blockDim.x + threadIdx.x;
    int total = batch * 256;
    if (idx >= 3 * total) return;
    int which = idx / total;
    int r = idx - which * total;
    int b = r >> 8;
    int c = r & 255;
    int node;
    if (which == 0) node = users[b];
    else if (which == 1) node = n_user + pos[b];
    else node = n_user + neg[b];
    out[idx] = all_e[(size_t)node * 256 + c];
}

static inline size_t align256(size_t x) { return (x + 255) & ~(size_t)255; }

extern "C" void kernel_launch(void* const* d_in, const int* in_sizes, int n_in,
                              void* d_out, int out_size, void* d_ws, size_t ws_size,
                              hipStream_t stream) {
    const float* user_emb = (const float*)d_in[0];
    const float* item_emb = (const float*)d_in[1];
    const float* W_gc = (const float*)d_in[2];
    const float* b_gc = (const float*)d_in[3];
    const float* W_bi = (const float*)d_in[4];
    const float* b_bi = (const float*)d_in[5];
    const float* edge_w = (const float*)d_in[6];
    const int* edge_src = (const int*)d_in[7];
    const int* edge_dst = (const int*)d_in[8];
    const int* users = (const int*)d_in[9];
    const int* pos = (const int*)d_in[10];
    const int* neg = (const int*)d_in[11];

    int n_user = in_sizes[0] / EMB;
    int n_item = in_sizes[1] / EMB;
    int N = n_user + n_item;
    int M = in_sizes[6];
    int layers = in_sizes[2] / (EMB * EMB);
    int batch = in_sizes[9];
    float* out = (float*)d_out;

    int nbuckets = (N + BROWS - 1) >> BSHIFT;   // 1172 for N=150000

    // workspace carve
    char* p = (char*)d_ws;
    float* ego = (float*)p;     p += align256((size_t)N * EMB * 4);
    float* side = (float*)p;    p += align256((size_t)N * EMB * 4);
    float* all_e = (float*)p;   p += align256((size_t)N * 256 * 4);
    int* bins = (int*)p;        p += align256((size_t)nbuckets * 4);
    int* off = (int*)p;         p += align256((size_t)(nbuckets + 1) * 4);
    int* cursor = (int*)p;      p += align256((size_t)nbuckets * 4);
    int2* entries = (int2*)p;   p += align256((size_t)M * 8);

    hipMemsetAsync(bins, 0, (size_t)nbuckets * 4, stream);

    k_init_ego<<<(N * EMB + 255) / 256, 256, 0, stream>>>(
        user_emb, item_emb, ego, all_e, n_user, N);

    // bucket build (once per launch; reused by all 3 layers)
    k_bhist<<<1024, 256, 0, stream>>>(edge_dst, bins, M, nbuckets);
    k_bscan<<<1, 1024, 0, stream>>>(bins, off, cursor, nbuckets);
    k_bfill<<<(M + 255) / 256, 256, 0, stream>>>(edge_src, edge_dst, edge_w,
                                                 cursor, entries, M);

    for (int k = 0; k < layers; k++) {
        k_side_lds<<<nbuckets, 256, 0, stream>>>(off, entries, ego, side, N);
        k_transform<<<(N + 255) / 256, 256, 0, stream>>>(
            side, ego, W_gc + (size_t)k * EMB * EMB, b_gc + (size_t)k * EMB,
            W_bi + (size_t)k * EMB * EMB, b_bi + (size_t)k * EMB,
            all_e, N, (k + 1) * EMB);
    }

    k_gather<<<(3 * batch * 256 + 255) / 256, 256, 0, stream>>>(
        all_e, users, pos, neg, out, n_user, batch);
}

// Round 6
// 2155.580 us; speedup vs baseline: 2.7346x; 2.7346x over previous
//
#include <hip/hip_runtime.h>

#define EMB 64
#define BSHIFT 7                      // 128 rows per bucket
#define BROWS (1 << BSHIFT)

// ---------------------------------------------------------------------------
// ego = concat(user_emb, item_emb); also write into all_e[:, 0:64]
// ---------------------------------------------------------------------------
__global__ void k_init_ego(const float* __restrict__ user_emb,
                           const float* __restrict__ item_emb,
                           float* __restrict__ ego, float* __restrict__ all_e,
                           int n_user, int N) {
    int idx = blockIdx.x * blockDim.x + threadIdx.x;
    int total = N * EMB;
    if (idx >= total) return;
    int n = idx >> 6;
    int c = idx & 63;
    float v = (n < n_user) ? user_emb[idx] : item_emb[(size_t)(n - n_user) * EMB + c];
    ego[idx] = v;
    all_e[(size_t)n * 256 + c] = v;
}

// ---------------------------------------------------------------------------
// Degree histogram over edge_dst (atomics on N counters, L2-resident)
// ---------------------------------------------------------------------------
__global__ void k_hist(const int* __restrict__ dst, int* __restrict__ counts, int M) {
    int e = blockIdx.x * blockDim.x + threadIdx.x;
    if (e >= M) return;
    atomicAdd(&counts[dst[e]], 1);
}

// ---------------------------------------------------------------------------
// Bucket offsets: bin[b] = sum of counts[b*128 .. b*128+127], exclusive scan
// -> off[0..P], cursor copy; also row_ptr[N] = M. Single block.
// ---------------------------------------------------------------------------
__global__ __launch_bounds__(1024) void k_bscan(const int* __restrict__ counts,
                                                int* __restrict__ off,
                                                int* __restrict__ cursor,
                                                int* __restrict__ row_ptr,
                                                int P, int N) {
    __shared__ int part[1024];
    int tid = threadIdx.x;
    int chunk = (P + 1023) / 1024;      // 2 for N=150000
    int lo = tid * chunk, hi = min(lo + chunk, P);
    int bsum[8];                         // chunk <= 8 supported
    int s = 0;
    for (int i = lo; i < hi; i++) {
        int rlo = i << BSHIFT, rhi = min(rlo + BROWS, N);
        int bs = 0;
        for (int r = rlo; r < rhi; r++) bs += counts[r];
        bsum[i - lo] = bs;
        s += bs;
    }
    part[tid] = s;
    __syncthreads();
    for (int d = 1; d < 1024; d <<= 1) {
        int add = (tid >= d) ? part[tid - d] : 0;
        __syncthreads();
        part[tid] += add;
        __syncthreads();
    }
    int o = part[tid] - s;
    for (int i = lo; i < hi; i++) {
        off[i] = o;
        cursor[i] = o;
        o += bsum[i - lo];
    }
    if (tid == 1023) {
        off[P] = o;
        row_ptr[N] = o;
    }
}

// ---------------------------------------------------------------------------
// In-place counts -> dsq : dsq[i] = deg>0 ? 1/sqrt(deg) : 0   (same buffer)
// ---------------------------------------------------------------------------
__global__ void k_dsq(int* __restrict__ counts, int N) {
    int i = blockIdx.x * 256 + threadIdx.x;
    if (i >= N) return;
    int d = counts[i];
    float v = (d > 0) ? 1.0f / sqrtf((float)d) : 0.0f;
    ((float*)counts)[i] = v;
}

// ---------------------------------------------------------------------------
// Bucket fill: bent[pos] = src<<7 | dst&127 ; 1172 append streams keep tail
// lines hot (near-sequential writeback, 4B/edge)
// ---------------------------------------------------------------------------
__global__ void k_bfill(const int* __restrict__ src, const int* __restrict__ dst,
                        int* __restrict__ cursor, int* __restrict__ bent, int M) {
    int e = blockIdx.x * 256 + threadIdx.x;
    if (e >= M) return;
    int d = dst[e];
    int pos = atomicAdd(&cursor[d >> BSHIFT], 1);
    bent[pos] = (src[e] << BSHIFT) | (d & (BROWS - 1));
}

// ---------------------------------------------------------------------------
// Per-bucket CSR finalize: one block per bucket. LDS 128-row histogram ->
// LDS scan -> row_ptr -> scatter src into the bucket's contiguous csr slice
// (~14 KB window, L2-hot).
// ---------------------------------------------------------------------------
__global__ __launch_bounds__(256) void k_csr_bucket(
        const int* __restrict__ off, const int* __restrict__ bent,
        int* __restrict__ row_ptr, int* __restrict__ csr, int N) {
    __shared__ int hist[BROWS];
    __shared__ int scan[BROWS];
    int b = blockIdx.x;
    int beg = off[b], end = off[b + 1];
    int tid = threadIdx.x;
    if (tid < BROWS) hist[tid] = 0;
    __syncthreads();
    for (int e = beg + tid; e < end; e += 256)
        atomicAdd(&hist[bent[e] & (BROWS - 1)], 1);
    __syncthreads();
    if (tid < BROWS) scan[tid] = hist[tid];
    __syncthreads();
    for (int d = 1; d < BROWS; d <<= 1) {
        int add = (tid >= d && tid < BROWS) ? scan[tid - d] : 0;
        __syncthreads();
        if (tid < BROWS) scan[tid] += add;
        __syncthreads();
    }
    if (tid < BROWS) {
        int excl = beg + scan[tid] - hist[tid];
        int node = (b << BSHIFT) + tid;
        if (node < N) row_ptr[node] = excl;
        hist[tid] = excl;            // reuse as per-row cursor
    }
    __syncthreads();
    for (int e = beg + tid; e < end; e += 256) {
        int m = bent[e];
        int pos = atomicAdd(&hist[m & (BROWS - 1)], 1);
        csr[pos] = m >> BSHIFT;
    }
}

// ---------------------------------------------------------------------------
// side[n] = dsq[n] * sum_{src in row n} dsq[src] * ego[src]
// one wave per node, lane = component, register accumulators, no atomics
// ---------------------------------------------------------------------------
__global__ __launch_bounds__(256) void k_side(const int* __restrict__ row_ptr,
                                              const int* __restrict__ csr,
                                              const float* __restrict__ dsq,
                                              const float* __restrict__ ego,
                                              float* __restrict__ side, int N) {
    int wave = threadIdx.x >> 6;
    int lane = threadIdx.x & 63;
    int n = blockIdx.x * 4 + wave;
    if (n >= N) return;
    int beg = row_ptr[n];
    int end = row_ptr[n + 1];
    float a0 = 0.f, a1 = 0.f, a2 = 0.f, a3 = 0.f;
    int e = beg;
    while ((e & 3) && e < end) {              // peel to 16B alignment
        int s = csr[e];
        a0 += dsq[s] * ego[(size_t)s * EMB + lane];
        e++;
    }
    for (; e + 4 <= end; e += 4) {
        int4 p = *(const int4*)(csr + e);
        float w0 = dsq[p.x], w1 = dsq[p.y], w2 = dsq[p.z], w3 = dsq[p.w];
        a0 += w0 * ego[(size_t)p.x * EMB + lane];
        a1 += w1 * ego[(size_t)p.y * EMB + lane];
        a2 += w2 * ego[(size_t)p.z * EMB + lane];
        a3 += w3 * ego[(size_t)p.w * EMB + lane];
    }
    for (; e < end; e++) {
        int s = csr[e];
        a0 += dsq[s] * ego[(size_t)s * EMB + lane];
    }
    side[(size_t)n * EMB + lane] = dsq[n] * ((a0 + a1) + (a2 + a3));
}

// ---------------------------------------------------------------------------
// Fused transform: out = leaky_relu(side@Wgc + bgc + (ego*side)@Wbi + bbi)
// ego <- out (in place); all_e[:,col] <- out/||out||.
// Thread = 4 rows x 16 cols; W broadcast from LDS; X from global as float4.
// ---------------------------------------------------------------------------
__global__ __launch_bounds__(256) void k_transform(
        const float* __restrict__ side, float* __restrict__ ego,
        const float* __restrict__ Wgc, const float* __restrict__ bgc,
        const float* __restrict__ Wbi, const float* __restrict__ bbi,
        float* __restrict__ all_e, int N, int layer_col) {
    __shared__ float sW[128][64];   // rows 0-63: Wgc, rows 64-127: Wbi
    __shared__ float sB[64];
    int tid = threadIdx.x;
    for (int i = tid; i < 64 * 64; i += 256) {
        sW[i >> 6][i & 63] = Wgc[i];
        sW[64 + (i >> 6)][i & 63] = Wbi[i];
    }
    if (tid < 64) sB[tid] = bgc[tid] + bbi[tid];
    __syncthreads();

    int cg = tid & 3;
    int rg = tid >> 2;
    int c0 = cg * 16;
    int r0 = blockIdx.x * 256 + rg * 4;

    float acc[4][16];
#pragma unroll
    for (int rr = 0; rr < 4; rr++)
#pragma unroll
        for (int c = 0; c < 16; c++) acc[rr][c] = sB[c0 + c];

    int ri[4];
#pragma unroll
    for (int rr = 0; rr < 4; rr++) ri[rr] = min(r0 + rr, N - 1);

    const float4* side4 = (const float4*)side;
    const float4* ego4 = (const float4*)ego;

#pragma unroll 1
    for (int kq = 0; kq < 16; kq++) {
        float4 x[4];
#pragma unroll
        for (int rr = 0; rr < 4; rr++) x[rr] = side4[(size_t)ri[rr] * 16 + kq];
#pragma unroll
        for (int kk = 0; kk < 4; kk++) {
            int k = kq * 4 + kk;
#pragma unroll
            for (int cq = 0; cq < 4; cq++) {
                float4 w = *(const float4*)&sW[k][c0 + cq * 4];
#pragma unroll
                for (int rr = 0; rr < 4; rr++) {
                    float xv = (&x[rr].x)[kk];
                    acc[rr][cq * 4 + 0] += xv * w.x;
                    acc[rr][cq * 4 + 1] += xv * w.y;
                    acc[rr][cq * 4 + 2] += xv * w.z;
                    acc[rr][cq * 4 + 3] += xv * w.w;
                }
            }
        }
    }

#pragma unroll 1
    for (int kq = 0; kq < 16; kq++) {
        float4 x[4];
#pragma unroll
        for (int rr = 0; rr < 4; rr++) {
            float4 a = ego4[(size_t)ri[rr] * 16 + kq];
            float4 b = side4[(size_t)ri[rr] * 16 + kq];
            x[rr] = make_float4(a.x * b.x, a.y * b.y, a.z * b.z, a.w * b.w);
        }
#pragma unroll
        for (int kk = 0; kk < 4; kk++) {
            int k = 64 + kq * 4 + kk;
#pragma unroll
            for (int cq = 0; cq < 4; cq++) {
                float4 w = *(const float4*)&sW[k][c0 + cq * 4];
#pragma unroll
                for (int rr = 0; rr < 4; rr++) {
                    float xv = (&x[rr].x)[kk];
                    acc[rr][cq * 4 + 0] += xv * w.x;
                    acc[rr][cq * 4 + 1] += xv * w.y;
                    acc[rr][cq * 4 + 2] += xv * w.z;
                    acc[rr][cq * 4 + 3] += xv * w.w;
                }
            }
        }
    }

#pragma unroll
    for (int rr = 0; rr < 4; rr++) {
        float s = 0.f;
#pragma unroll
        for (int c = 0; c < 16; c++) {
            float v = acc[rr][c];
            v = v > 0.f ? v : 0.2f * v;
            acc[rr][c] = v;
            s += v * v;
        }
        s += __shfl_xor(s, 1, 64);
        s += __shfl_xor(s, 2, 64);
        float inv = 1.0f / fmaxf(sqrtf(s), 1e-12f);
        int row = r0 + rr;
        if (row < N) {
            float4* pe = (float4*)&ego[(size_t)row * EMB + c0];
            float4* pa = (float4*)&all_e[(size_t)row * 256 + layer_col + c0];
#pragma unroll
            for (int cq = 0; cq < 4; cq++) {
                float4 v = make_float4(acc[rr][cq * 4 + 0], acc[rr][cq * 4 + 1],
                                       acc[rr][cq * 4 + 2], acc[rr][cq * 4 + 3]);
                pe[cq] = v;
                pa[cq] = make_float4(v.x * inv, v.y * inv, v.z * inv, v.w * inv);
            }
        }
    }
}

// ---------------------------------------------------------------------------
// out = [all_e[users], all_e[n_user+pos], all_e[n_user+neg]]  (each B x 256)
// ---------------------------------------------------------------------------
__global__ void k_gather(const float* __restrict__ all_e,
                         const int* __restrict__ users,
                         const int* __restrict__ pos,
                         const int* __restrict__ neg,
                         float* __restrict__ out, int n_user, int batch) {
    int idx = blockIdx.x * blockDim.x + threadIdx.x;
    int total = batch * 256;
    if (idx >= 3 * total) return;
    int which = idx / total;
    int r = idx - which * total;
    int b = r >> 8;
    int c = r & 255;
    int node;
    if (which == 0) node = users[b];
    else if (which == 1) node = n_user + pos[b];
    else node = n_user + neg[b];
    out[idx] = all_e[(size_t)node * 256 + c];
}

static inline size_t align256(size_t x) { return (x + 255) & ~(size_t)255; }

extern "C" void kernel_launch(void* const* d_in, const int* in_sizes, int n_in,
                              void* d_out, int out_size, void* d_ws, size_t ws_size,
                              hipStream_t stream) {
    const float* user_emb = (const float*)d_in[0];
    const float* item_emb = (const float*)d_in[1];
    const float* W_gc = (const float*)d_in[2];
    const float* b_gc = (const float*)d_in[3];
    const float* W_bi = (const float*)d_in[4];
    const float* b_bi = (const float*)d_in[5];
    const int* edge_src = (const int*)d_in[7];
    const int* edge_dst = (const int*)d_in[8];
    const int* users = (const int*)d_in[9];
    const int* pos = (const int*)d_in[10];
    const int* neg = (const int*)d_in[11];

    int n_user = in_sizes[0] / EMB;
    int n_item = in_sizes[1] / EMB;
    int N = n_user + n_item;
    int M = in_sizes[6];
    int layers = in_sizes[2] / (EMB * EMB);
    int batch = in_sizes[9];
    float* out = (float*)d_out;

    int nbuckets = (N + BROWS - 1) >> BSHIFT;   // 1172 for N=150000

    // workspace carve (~263.7 MB total — within round-3's proven budget)
    char* p = (char*)d_ws;
    float* ego = (float*)p;     p += align256((size_t)N * EMB * 4);
    float* side = (float*)p;    p += align256((size_t)N * EMB * 4);
    float* all_e = (float*)p;   p += align256((size_t)N * 256 * 4);
    int* counts = (int*)p;      p += align256((size_t)N * 4);       // -> dsq
    int* off = (int*)p;         p += align256((size_t)(nbuckets + 1) * 4);
    int* cursor = (int*)p;      p += align256((size_t)nbuckets * 4);
    int* row_ptr = (int*)p;     p += align256((size_t)(N + 1) * 4);
    int* bent = (int*)p;        p += align256((size_t)M * 4);
    int* csr = (int*)p;         p += align256((size_t)M * 4);

    hipMemsetAsync(counts, 0, (size_t)N * 4, stream);

    k_init_ego<<<(N * EMB + 255) / 256, 256, 0, stream>>>(
        user_emb, item_emb, ego, all_e, n_user, N);

    // two-level CSR build (once per launch; reused by all 3 layers)
    k_hist<<<(M + 255) / 256, 256, 0, stream>>>(edge_dst, counts, M);
    k_bscan<<<1, 1024, 0, stream>>>(counts, off, cursor, row_ptr, nbuckets, N);
    k_dsq<<<(N + 255) / 256, 256, 0, stream>>>(counts, N);   // counts -> dsq
    k_bfill<<<(M + 255) / 256, 256, 0, stream>>>(edge_src, edge_dst,
                                                 cursor, bent, M);
    k_csr_bucket<<<nbuckets, 256, 0, stream>>>(off, bent, row_ptr, csr, N);

    const float* dsq = (const float*)counts;
    for (int k = 0; k < layers; k++) {
        k_side<<<(N + 3) / 4, 256, 0, stream>>>(row_ptr, csr, dsq, ego, side, N);
        k_transform<<<(N + 255) / 256, 256, 0, stream>>>(
            side, ego, W_gc + (size_t)k * EMB * EMB, b_gc + (size_t)k * EMB,
            W_bi + (size_t)k * EMB * EMB, b_bi + (size_t)k * EMB,
            all_e, N, (k + 1) * EMB);
    }

    k_gather<<<(3 * batch * 256 + 255) / 256, 256, 0, stream>>>(
        all_e, users, pos, neg, out, n_user, batch);
}

// Round 7
// 1327.972 us; speedup vs baseline: 4.4389x; 1.6232x over previous
//
#include <hip/hip_runtime.h>

#define EMB 64

// ---------------------------------------------------------------------------
// ego = concat(user_emb, item_emb); also write into all_e[:, 0:64]
// ---------------------------------------------------------------------------
__global__ void k_init_ego(const float* __restrict__ user_emb,
                           const float* __restrict__ item_emb,
                           float* __restrict__ ego, float* __restrict__ all_e,
                           int n_user, int N) {
    int idx = blockIdx.x * blockDim.x + threadIdx.x;
    int total = N * EMB;
    if (idx >= total) return;
    int n = idx >> 6;
    int c = idx & 63;
    float v = (n < n_user) ? user_emb[idx] : item_emb[(size_t)(n - n_user) * EMB + c];
    ego[idx] = v;
    all_e[(size_t)n * 256 + c] = v;
}

// ---------------------------------------------------------------------------
// Degree histogram over edge_dst (atomics on N counters, L2-resident;
// 150K counters -> ~27 hits each, low contention)
// ---------------------------------------------------------------------------
__global__ void k_hist(const int* __restrict__ dst, int* __restrict__ counts, int M) {
    int e = blockIdx.x * blockDim.x + threadIdx.x;
    if (e >= M) return;
    atomicAdd(&counts[dst[e]], 1);
}

// ---------------------------------------------------------------------------
// Scan stage 1: per-block (256 elems) sum of counts -> partial[block]
// ---------------------------------------------------------------------------
__global__ __launch_bounds__(256) void k_blocksum(const int* __restrict__ counts,
                                                  int* __restrict__ partial, int N) {
    int i = blockIdx.x * 256 + threadIdx.x;
    int v = (i < N) ? counts[i] : 0;
#pragma unroll
    for (int off = 32; off > 0; off >>= 1) v += __shfl_down(v, off, 64);
    __shared__ int ws[4];
    int wave = threadIdx.x >> 6, lane = threadIdx.x & 63;
    if (lane == 0) ws[wave] = v;
    __syncthreads();
    if (threadIdx.x == 0) partial[blockIdx.x] = ws[0] + ws[1] + ws[2] + ws[3];
}

// ---------------------------------------------------------------------------
// Scan stage 2: exclusive scan of P partials in-place (single block, tiled)
// ---------------------------------------------------------------------------
__global__ __launch_bounds__(1024) void k_scan_partials(int* __restrict__ partial, int P) {
    __shared__ int buf[1024];
    int tid = threadIdx.x;
    int carry = 0;
    for (int base = 0; base < P; base += 1024) {
        int i = base + tid;
        int v = (i < P) ? partial[i] : 0;
        buf[tid] = v;
        __syncthreads();
        for (int d = 1; d < 1024; d <<= 1) {
            int add = (tid >= d) ? buf[tid - d] : 0;
            __syncthreads();
            buf[tid] += add;
            __syncthreads();
        }
        if (i < P) partial[i] = carry + buf[tid] - v;   // exclusive
        carry += buf[1023];
        __syncthreads();
    }
}

// ---------------------------------------------------------------------------
// Scan stage 3: per-block exclusive scan + block offset -> row_ptr, cursor
// ---------------------------------------------------------------------------
__global__ __launch_bounds__(256) void k_rowptr(const int* __restrict__ counts,
                                                const int* __restrict__ partial,
                                                int* __restrict__ row_ptr,
                                                int* __restrict__ cursor, int N) {
    __shared__ int buf[256];
    int tid = threadIdx.x;
    int i = blockIdx.x * 256 + tid;
    int c = (i < N) ? counts[i] : 0;
    buf[tid] = c;
    __syncthreads();
    for (int d = 1; d < 256; d <<= 1) {
        int add = (tid >= d) ? buf[tid - d] : 0;
        __syncthreads();
        buf[tid] += add;
        __syncthreads();
    }
    int off = partial[blockIdx.x] + buf[tid] - c;   // exclusive prefix
    if (i < N) {
        row_ptr[i] = off;
        cursor[i] = off;
        if (i == N - 1) row_ptr[N] = off + c;
    }
}

// ---------------------------------------------------------------------------
// In-place counts -> dsq : dsq[i] = deg>0 ? 1/sqrt(deg) : 0   (same buffer)
// ---------------------------------------------------------------------------
__global__ void k_dsq(int* __restrict__ counts, int N) {
    int i = blockIdx.x * 256 + threadIdx.x;
    if (i >= N) return;
    int d = counts[i];
    float v = (d > 0) ? 1.0f / sqrtf((float)d) : 0.0f;
    ((float*)counts)[i] = v;
}

// ---------------------------------------------------------------------------
// CSR fill: csr[pos] = src at pos = cursor[dst]++  (4 B/edge payload)
// ---------------------------------------------------------------------------
__global__ void k_fill(const int* __restrict__ src, const int* __restrict__ dst,
                       int* __restrict__ cursor, int* __restrict__ csr, int M) {
    int e = blockIdx.x * blockDim.x + threadIdx.x;
    if (e >= M) return;
    int pos = atomicAdd(&cursor[dst[e]], 1);
    csr[pos] = src[e];
}

// ---------------------------------------------------------------------------
// side[n] = dsq[n] * sum_{src in row n} dsq[src] * ego[src]
// one wave per node, lane = component, 8 independent gathers in flight
// ---------------------------------------------------------------------------
__global__ __launch_bounds__(256) void k_side(const int* __restrict__ row_ptr,
                                              const int* __restrict__ csr,
                                              const float* __restrict__ dsq,
                                              const float* __restrict__ ego,
                                              float* __restrict__ side, int N) {
    int wave = threadIdx.x >> 6;
    int lane = threadIdx.x & 63;
    int n = blockIdx.x * 4 + wave;
    if (n >= N) return;
    int beg = row_ptr[n];
    int end = row_ptr[n + 1];
    float a0 = 0.f, a1 = 0.f, a2 = 0.f, a3 = 0.f;
    int e = beg;
    while ((e & 3) && e < end) {              // peel to 16B alignment
        int s = csr[e];
        a0 += dsq[s] * ego[(size_t)s * EMB + lane];
        e++;
    }
    for (; e + 8 <= end; e += 8) {
        int4 p = *(const int4*)(csr + e);
        int4 q = *(const int4*)(csr + e + 4);
        float v0 = ego[(size_t)p.x * EMB + lane];
        float v1 = ego[(size_t)p.y * EMB + lane];
        float v2 = ego[(size_t)p.z * EMB + lane];
        float v3 = ego[(size_t)p.w * EMB + lane];
        float v4 = ego[(size_t)q.x * EMB + lane];
        float v5 = ego[(size_t)q.y * EMB + lane];
        float v6 = ego[(size_t)q.z * EMB + lane];
        float v7 = ego[(size_t)q.w * EMB + lane];
        a0 += dsq[p.x] * v0;
        a1 += dsq[p.y] * v1;
        a2 += dsq[p.z] * v2;
        a3 += dsq[p.w] * v3;
        a0 += dsq[q.x] * v4;
        a1 += dsq[q.y] * v5;
        a2 += dsq[q.z] * v6;
        a3 += dsq[q.w] * v7;
    }
    for (; e + 4 <= end; e += 4) {
        int4 p = *(const int4*)(csr + e);
        a0 += dsq[p.x] * ego[(size_t)p.x * EMB + lane];
        a1 += dsq[p.y] * ego[(size_t)p.y * EMB + lane];
        a2 += dsq[p.z] * ego[(size_t)p.z * EMB + lane];
        a3 += dsq[p.w] * ego[(size_t)p.w * EMB + lane];
    }
    for (; e < end; e++) {
        int s = csr[e];
        a0 += dsq[s] * ego[(size_t)s * EMB + lane];
    }
    side[(size_t)n * EMB + lane] = dsq[n] * ((a0 + a1) + (a2 + a3));
}

// ---------------------------------------------------------------------------
// Fused transform: out = leaky_relu(side@Wgc + bgc + (ego*side)@Wbi + bbi)
// ego <- out (in place); all_e[:,col] <- out/||out||.
// Thread = 4 rows x 16 cols; W broadcast from LDS; X from global as float4.
// ---------------------------------------------------------------------------
__global__ __launch_bounds__(256) void k_transform(
        const float* __restrict__ side, float* __restrict__ ego,
        const float* __restrict__ Wgc, const float* __restrict__ bgc,
        const float* __restrict__ Wbi, const float* __restrict__ bbi,
        float* __restrict__ all_e, int N, int layer_col) {
    __shared__ float sW[128][64];   // rows 0-63: Wgc, rows 64-127: Wbi
    __shared__ float sB[64];
    int tid = threadIdx.x;
    for (int i = tid; i < 64 * 64; i += 256) {
        sW[i >> 6][i & 63] = Wgc[i];
        sW[64 + (i >> 6)][i & 63] = Wbi[i];
    }
    if (tid < 64) sB[tid] = bgc[tid] + bbi[tid];
    __syncthreads();

    int cg = tid & 3;
    int rg = tid >> 2;
    int c0 = cg * 16;
    int r0 = blockIdx.x * 256 + rg * 4;

    float acc[4][16];
#pragma unroll
    for (int rr = 0; rr < 4; rr++)
#pragma unroll
        for (int c = 0; c < 16; c++) acc[rr][c] = sB[c0 + c];

    int ri[4];
#pragma unroll
    for (int rr = 0; rr < 4; rr++) ri[rr] = min(r0 + rr, N - 1);

    const float4* side4 = (const float4*)side;
    const float4* ego4 = (const float4*)ego;

#pragma unroll 1
    for (int kq = 0; kq < 16; kq++) {
        float4 x[4];
#pragma unroll
        for (int rr = 0; rr < 4; rr++) x[rr] = side4[(size_t)ri[rr] * 16 + kq];
#pragma unroll
        for (int kk = 0; kk < 4; kk++) {
            int k = kq * 4 + kk;
#pragma unroll
            for (int cq = 0; cq < 4; cq++) {
                float4 w = *(const float4*)&sW[k][c0 + cq * 4];
#pragma unroll
                for (int rr = 0; rr < 4; rr++) {
                    float xv = (&x[rr].x)[kk];
                    acc[rr][cq * 4 + 0] += xv * w.x;
                    acc[rr][cq * 4 + 1] += xv * w.y;
                    acc[rr][cq * 4 + 2] += xv * w.z;
                    acc[rr][cq * 4 + 3] += xv * w.w;
                }
            }
        }
    }

#pragma unroll 1
    for (int kq = 0; kq < 16; kq++) {
        float4 x[4];
#pragma unroll
        for (int rr = 0; rr < 4; rr++) {
            float4 a = ego4[(size_t)ri[rr] * 16 + kq];
            float4 b = side4[(size_t)ri[rr] * 16 + kq];
            x[rr] = make_float4(a.x * b.x, a.y * b.y, a.z * b.z, a.w * b.w);
        }
#pragma unroll
        for (int kk = 0; kk < 4; kk++) {
            int k = 64 + kq * 4 + kk;
#pragma unroll
            for (int cq = 0; cq < 4; cq++) {
                float4 w = *(const float4*)&sW[k][c0 + cq * 4];
#pragma unroll
                for (int rr = 0; rr < 4; rr++) {
                    float xv = (&x[rr].x)[kk];
                    acc[rr][cq * 4 + 0] += xv * w.x;
                    acc[rr][cq * 4 + 1] += xv * w.y;
                    acc[rr][cq * 4 + 2] += xv * w.z;
                    acc[rr][cq * 4 + 3] += xv * w.w;
                }
            }
        }
    }

#pragma unroll
    for (int rr = 0; rr < 4; rr++) {
        float s = 0.f;
#pragma unroll
        for (int c = 0; c < 16; c++) {
            float v = acc[rr][c];
            v = v > 0.f ? v : 0.2f * v;
            acc[rr][c] = v;
            s += v * v;
        }
        s += __shfl_xor(s, 1, 64);
        s += __shfl_xor(s, 2, 64);
        float inv = 1.0f / fmaxf(sqrtf(s), 1e-12f);
        int row = r0 + rr;
        if (row < N) {
            float4* pe = (float4*)&ego[(size_t)row * EMB + c0];
            float4* pa = (float4*)&all_e[(size_t)row * 256 + layer_col + c0];
#pragma unroll
            for (int cq = 0; cq < 4; cq++) {
                float4 v = make_float4(acc[rr][cq * 4 + 0], acc[rr][cq * 4 + 1],
                                       acc[rr][cq * 4 + 2], acc[rr][cq * 4 + 3]);
                pe[cq] = v;
                pa[cq] = make_float4(v.x * inv, v.y * inv, v.z * inv, v.w * inv);
            }
        }
    }
}

// ---------------------------------------------------------------------------
// out = [all_e[users], all_e[n_user+pos], all_e[n_user+neg]]  (each B x 256)
// ---------------------------------------------------------------------------
__global__ void k_gather(const float* __restrict__ all_e,
                         const int* __restrict__ users,
                         const int* __restrict__ pos,
                         const int* __restrict__ neg,
                         float* __restrict__ out, int n_user, int batch) {
    int idx = blockIdx.x * blockDim.x + threadIdx.x;
    int total = batch * 256;
    if (idx >= 3 * total) return;
    int which = idx / total;
    int r = idx - which * total;
    int b = r >> 8;
    int c = r & 255;
    int node;
    if (which == 0) node = users[b];
    else if (which == 1) node = n_user + pos[b];
    else node = n_user + neg[b];
    out[idx] = all_e[(size_t)node * 256 + c];
}

static inline size_t align256(size_t x) { return (x + 255) & ~(size_t)255; }

extern "C" void kernel_launch(void* const* d_in, const int* in_sizes, int n_in,
                              void* d_out, int out_size, void* d_ws, size_t ws_size,
                              hipStream_t stream) {
    const float* user_emb = (const float*)d_in[0];
    const float* item_emb = (const float*)d_in[1];
    const float* W_gc = (const float*)d_in[2];
    const float* b_gc = (const float*)d_in[3];
    const float* W_bi = (const float*)d_in[4];
    const float* b_bi = (const float*)d_in[5];
    const int* edge_src = (const int*)d_in[7];
    const int* edge_dst = (const int*)d_in[8];
    const int* users = (const int*)d_in[9];
    const int* pos = (const int*)d_in[10];
    const int* neg = (const int*)d_in[11];

    int n_user = in_sizes[0] / EMB;
    int n_item = in_sizes[1] / EMB;
    int N = n_user + n_item;
    int M = in_sizes[6];
    int layers = in_sizes[2] / (EMB * EMB);
    int batch = in_sizes[9];
    float* out = (float*)d_out;

    int nblk = (N + 255) / 256;   // scan blocks

    // workspace carve (~248 MB total — within proven budget)
    char* p = (char*)d_ws;
    float* ego = (float*)p;     p += align256((size_t)N * EMB * 4);
    float* side = (float*)p;    p += align256((size_t)N * EMB * 4);
    float* all_e = (float*)p;   p += align256((size_t)N * 256 * 4);
    int* counts = (int*)p;      p += align256((size_t)N * 4);       // -> dsq
    int* row_ptr = (int*)p;     p += align256((size_t)(N + 1) * 4);
    int* cursor = (int*)p;      p += align256((size_t)N * 4);
    int* partial = (int*)p;     p += align256((size_t)nblk * 4);
    int* csr = (int*)p;         p += align256((size_t)M * 4);

    hipMemsetAsync(counts, 0, (size_t)N * 4, stream);

    k_init_ego<<<(N * EMB + 255) / 256, 256, 0, stream>>>(
        user_emb, item_emb, ego, all_e, n_user, N);

    // CSR build (once per launch; reused by all 3 layers)
    k_hist<<<(M + 255) / 256, 256, 0, stream>>>(edge_dst, counts, M);
    k_blocksum<<<nblk, 256, 0, stream>>>(counts, partial, N);
    k_scan_partials<<<1, 1024, 0, stream>>>(partial, nblk);
    k_rowptr<<<nblk, 256, 0, stream>>>(counts, partial, row_ptr, cursor, N);
    k_dsq<<<(N + 255) / 256, 256, 0, stream>>>(counts, N);   // counts -> dsq
    k_fill<<<(M + 255) / 256, 256, 0, stream>>>(edge_src, edge_dst,
                                                cursor, csr, M);

    const float* dsq = (const float*)counts;
    for (int k = 0; k < layers; k++) {
        k_side<<<(N + 3) / 4, 256, 0, stream>>>(row_ptr, csr, dsq, ego, side, N);
        k_transform<<<(N + 255) / 256, 256, 0, stream>>>(
            side, ego, W_gc + (size_t)k * EMB * EMB, b_gc + (size_t)k * EMB,
            W_bi + (size_t)k * EMB * EMB, b_bi + (size_t)k * EMB,
            all_e, N, (k + 1) * EMB);
    }

    k_gather<<<(3 * batch * 256 + 255) / 256, 256, 0, stream>>>(
        all_e, users, pos, neg, out, n_user, batch);
}

// Round 8
// 1099.393 us; speedup vs baseline: 5.3618x; 1.2079x over previous
//
#include <hip/hip_runtime.h>

#define EMB 64
#define B2SHIFT 8                 // 256 dst rows per bucket
#define B2ROWS 256
#define MAXB 1024                 // LDS hist capacity (586 buckets actual)

__device__ __forceinline__ float b2f(unsigned short u) {
    return __uint_as_float(((unsigned int)u) << 16);
}
__device__ __forceinline__ unsigned short f2b(float f) {
    unsigned int u = __float_as_uint(f);
    u += 0x7FFF + ((u >> 16) & 1);          // round-to-nearest-even
    return (unsigned short)(u >> 16);
}

// ---------------------------------------------------------------------------
// ego = concat(user_emb, item_emb) (f32 + bf16 copies); all_e[:,0:64] = bf16
// ---------------------------------------------------------------------------
__global__ void k_init_ego(const float* __restrict__ user_emb,
                           const float* __restrict__ item_emb,
                           float* __restrict__ ego, unsigned short* __restrict__ egob,
                           unsigned short* __restrict__ all_eb,
                           int n_user, int N) {
    int idx = blockIdx.x * blockDim.x + threadIdx.x;
    int total = N * EMB;
    if (idx >= total) return;
    int n = idx >> 6;
    int c = idx & 63;
    float v = (n < n_user) ? user_emb[idx] : item_emb[(size_t)(n - n_user) * EMB + c];
    ego[idx] = v;
    unsigned short b = f2b(v);
    egob[idx] = b;
    all_eb[(size_t)n * 256 + c] = b;
}

// ---------------------------------------------------------------------------
// Degree histogram over edge_dst (150K L2-resident counters, low contention)
// ---------------------------------------------------------------------------
__global__ void k_hist(const int* __restrict__ dst, int* __restrict__ counts, int M) {
    int e = blockIdx.x * blockDim.x + threadIdx.x;
    if (e >= M) return;
    atomicAdd(&counts[dst[e]], 1);
}

// ---------------------------------------------------------------------------
// Scan stage 1: per-block (256) sums
// ---------------------------------------------------------------------------
__global__ __launch_bounds__(256) void k_blocksum(const int* __restrict__ counts,
                                                  int* __restrict__ partial, int N) {
    int i = blockIdx.x * 256 + threadIdx.x;
    int v = (i < N) ? counts[i] : 0;
#pragma unroll
    for (int off = 32; off > 0; off >>= 1) v += __shfl_down(v, off, 64);
    __shared__ int ws[4];
    int wave = threadIdx.x >> 6, lane = threadIdx.x & 63;
    if (lane == 0) ws[wave] = v;
    __syncthreads();
    if (threadIdx.x == 0) partial[blockIdx.x] = ws[0] + ws[1] + ws[2] + ws[3];
}

// ---------------------------------------------------------------------------
// Scan stage 2: exclusive scan of partials (single block, tiled)
// ---------------------------------------------------------------------------
__global__ __launch_bounds__(1024) void k_scan_partials(int* __restrict__ partial, int P) {
    __shared__ int buf[1024];
    int tid = threadIdx.x;
    int carry = 0;
    for (int base = 0; base < P; base += 1024) {
        int i = base + tid;
        int v = (i < P) ? partial[i] : 0;
        buf[tid] = v;
        __syncthreads();
        for (int d = 1; d < 1024; d <<= 1) {
            int add = (tid >= d) ? buf[tid - d] : 0;
            __syncthreads();
            buf[tid] += add;
            __syncthreads();
        }
        if (i < P) partial[i] = carry + buf[tid] - v;
        carry += buf[1023];
        __syncthreads();
    }
}

// ---------------------------------------------------------------------------
// Scan stage 3: per-block exclusive scan + offset -> row_ptr
// ---------------------------------------------------------------------------
__global__ __launch_bounds__(256) void k_rowptr(const int* __restrict__ counts,
                                                const int* __restrict__ partial,
                                                int* __restrict__ row_ptr, int N) {
    __shared__ int buf[256];
    int tid = threadIdx.x;
    int i = blockIdx.x * 256 + tid;
    int c = (i < N) ? counts[i] : 0;
    buf[tid] = c;
    __syncthreads();
    for (int d = 1; d < 256; d <<= 1) {
        int add = (tid >= d) ? buf[tid - d] : 0;
        __syncthreads();
        buf[tid] += add;
        __syncthreads();
    }
    int off = partial[blockIdx.x] + buf[tid] - c;
    if (i < N) {
        row_ptr[i] = off;
        if (i == N - 1) row_ptr[N] = off + c;
    }
}

// ---------------------------------------------------------------------------
// In-place counts -> dsq
// ---------------------------------------------------------------------------
__global__ void k_dsq(int* __restrict__ counts, int N) {
    int i = blockIdx.x * 256 + threadIdx.x;
    if (i >= N) return;
    int d = counts[i];
    float v = (d > 0) ? 1.0f / sqrtf((float)d) : 0.0f;
    ((float*)counts)[i] = v;
}

// ---------------------------------------------------------------------------
// bcur[b] = row_ptr[b<<8]  (bucket bases are row_ptr at bucket boundaries)
// ---------------------------------------------------------------------------
__global__ void k_bcur(const int* __restrict__ row_ptr, int* __restrict__ bcur,
                       int nb2, int N) {
    int b = blockIdx.x * 256 + threadIdx.x;
    if (b >= nb2) return;
    bcur[b] = row_ptr[min(b << B2SHIFT, N)];
}

// ---------------------------------------------------------------------------
// Multisplit pass 1: per-block LDS bucket histogram -> one global reservation
// per (block,bucket) -> append edges into block-private runs. Runs are
// single-writer => full lines assembled in one XCD's L2 before writeback.
// binned entry = (src << 8) | (dst & 255)
// ---------------------------------------------------------------------------
__global__ __launch_bounds__(256) void k_bin(const int* __restrict__ src,
                                             const int* __restrict__ dst,
                                             int* __restrict__ bcur,
                                             int* __restrict__ binned,
                                             int M, int nb2) {
    __shared__ int hist[MAXB];
    __shared__ int runcur[MAXB];
    int chunk = (M + gridDim.x - 1) / gridDim.x;
    int lo = blockIdx.x * chunk;
    int hi = min(lo + chunk, M);
    for (int i = threadIdx.x; i < nb2; i += 256) hist[i] = 0;
    __syncthreads();
    for (int e = lo + threadIdx.x; e < hi; e += 256)
        atomicAdd(&hist[dst[e] >> B2SHIFT], 1);
    __syncthreads();
    for (int i = threadIdx.x; i < nb2; i += 256) {
        int c = hist[i];
        runcur[i] = c ? atomicAdd(&bcur[i], c) : 0;
    }
    __syncthreads();
    for (int e = lo + threadIdx.x; e < hi; e += 256) {
        int d = dst[e];
        int pos = atomicAdd(&runcur[d >> B2SHIFT], 1);
        binned[pos] = (src[e] << B2SHIFT) | (d & (B2ROWS - 1));
    }
}

// ---------------------------------------------------------------------------
// Multisplit pass 2: one block per bucket. LDS per-node cursors (init from
// row_ptr); scatter src into the bucket's ~27KB csr window (single writer,
// L2-resident, full-line writeback).
// ---------------------------------------------------------------------------
__global__ __launch_bounds__(256) void k_csrb(const int* __restrict__ row_ptr,
                                              const int* __restrict__ binned,
                                              int* __restrict__ csr, int N) {
    __shared__ int cur[B2ROWS];
    int b = blockIdx.x;
    int node0 = b << B2SHIFT;
    int beg = row_ptr[min(node0, N)];
    int end = row_ptr[min(node0 + B2ROWS, N)];
    int node = node0 + threadIdx.x;
    cur[threadIdx.x] = (node < N) ? row_ptr[node] : 0;
    __syncthreads();
    for (int e = beg + (int)threadIdx.x; e < end; e += 256) {
        int v = binned[e];
        int pos = atomicAdd(&cur[v & (B2ROWS - 1)], 1);
        csr[pos] = v >> B2SHIFT;
    }
}

// ---------------------------------------------------------------------------
// side[n] = dsq[n] * sum dsq[src] * ego_bf16[src]  — one wave per node,
// lane = component, bf16 rows (128B/gather, half the L3 traffic), 8 in flight
// ---------------------------------------------------------------------------
__global__ __launch_bounds__(256) void k_side(const int* __restrict__ row_ptr,
                                              const int* __restrict__ csr,
                                              const float* __restrict__ dsq,
                                              const unsigned short* __restrict__ egob,
                                              float* __restrict__ side, int N) {
    int wave = threadIdx.x >> 6;
    int lane = threadIdx.x & 63;
    int n = blockIdx.x * 4 + wave;
    if (n >= N) return;
    int beg = row_ptr[n];
    int end = row_ptr[n + 1];
    float a0 = 0.f, a1 = 0.f, a2 = 0.f, a3 = 0.f;
    int e = beg;
    while ((e & 3) && e < end) {
        int s = csr[e];
        a0 += dsq[s] * b2f(egob[(size_t)s * EMB + lane]);
        e++;
    }
    for (; e + 8 <= end; e += 8) {
        int4 p = *(const int4*)(csr + e);
        int4 q = *(const int4*)(csr + e + 4);
        float v0 = b2f(egob[(size_t)p.x * EMB + lane]);
        float v1 = b2f(egob[(size_t)p.y * EMB + lane]);
        float v2 = b2f(egob[(size_t)p.z * EMB + lane]);
        float v3 = b2f(egob[(size_t)p.w * EMB + lane]);
        float v4 = b2f(egob[(size_t)q.x * EMB + lane]);
        float v5 = b2f(egob[(size_t)q.y * EMB + lane]);
        float v6 = b2f(egob[(size_t)q.z * EMB + lane]);
        float v7 = b2f(egob[(size_t)q.w * EMB + lane]);
        a0 += dsq[p.x] * v0;
        a1 += dsq[p.y] * v1;
        a2 += dsq[p.z] * v2;
        a3 += dsq[p.w] * v3;
        a0 += dsq[q.x] * v4;
        a1 += dsq[q.y] * v5;
        a2 += dsq[q.z] * v6;
        a3 += dsq[q.w] * v7;
    }
    for (; e + 4 <= end; e += 4) {
        int4 p = *(const int4*)(csr + e);
        a0 += dsq[p.x] * b2f(egob[(size_t)p.x * EMB + lane]);
        a1 += dsq[p.y] * b2f(egob[(size_t)p.y * EMB + lane]);
        a2 += dsq[p.z] * b2f(egob[(size_t)p.z * EMB + lane]);
        a3 += dsq[p.w] * b2f(egob[(size_t)p.w * EMB + lane]);
    }
    for (; e < end; e++) {
        int s = csr[e];
        a0 += dsq[s] * b2f(egob[(size_t)s * EMB + lane]);
    }
    side[(size_t)n * EMB + lane] = dsq[n] * ((a0 + a1) + (a2 + a3));
}

// ---------------------------------------------------------------------------
// Fused transform: out = leaky_relu(side@Wgc + bgc + (ego*side)@Wbi + bbi)
// ego(f32) <- out; egob(bf16) <- out; all_eb[:,col] <- bf16(out/||out||)
// ---------------------------------------------------------------------------
__global__ __launch_bounds__(256) void k_transform(
        const float* __restrict__ side, float* __restrict__ ego,
        unsigned short* __restrict__ egob,
        const float* __restrict__ Wgc, const float* __restrict__ bgc,
        const float* __restrict__ Wbi, const float* __restrict__ bbi,
        unsigned short* __restrict__ all_eb, int N, int layer_col) {
    __shared__ float sW[128][64];
    __shared__ float sB[64];
    int tid = threadIdx.x;
    for (int i = tid; i < 64 * 64; i += 256) {
        sW[i >> 6][i & 63] = Wgc[i];
        sW[64 + (i >> 6)][i & 63] = Wbi[i];
    }
    if (tid < 64) sB[tid] = bgc[tid] + bbi[tid];
    __syncthreads();

    int cg = tid & 3;
    int rg = tid >> 2;
    int c0 = cg * 16;
    int r0 = blockIdx.x * 256 + rg * 4;

    float acc[4][16];
#pragma unroll
    for (int rr = 0; rr < 4; rr++)
#pragma unroll
        for (int c = 0; c < 16; c++) acc[rr][c] = sB[c0 + c];

    int ri[4];
#pragma unroll
    for (int rr = 0; rr < 4; rr++) ri[rr] = min(r0 + rr, N - 1);

    const float4* side4 = (const float4*)side;
    const float4* ego4 = (const float4*)ego;

#pragma unroll 1
    for (int kq = 0; kq < 16; kq++) {
        float4 x[4];
#pragma unroll
        for (int rr = 0; rr < 4; rr++) x[rr] = side4[(size_t)ri[rr] * 16 + kq];
#pragma unroll
        for (int kk = 0; kk < 4; kk++) {
            int k = kq * 4 + kk;
#pragma unroll
            for (int cq = 0; cq < 4; cq++) {
                float4 w = *(const float4*)&sW[k][c0 + cq * 4];
#pragma unroll
                for (int rr = 0; rr < 4; rr++) {
                    float xv = (&x[rr].x)[kk];
                    acc[rr][cq * 4 + 0] += xv * w.x;
                    acc[rr][cq * 4 + 1] += xv * w.y;
                    acc[rr][cq * 4 + 2] += xv * w.z;
                    acc[rr][cq * 4 + 3] += xv * w.w;
                }
            }
        }
    }

#pragma unroll 1
    for (int kq = 0; kq < 16; kq++) {
        float4 x[4];
#pragma unroll
        for (int rr = 0; rr < 4; rr++) {
            float4 a = ego4[(size_t)ri[rr] * 16 + kq];
            float4 b = side4[(size_t)ri[rr] * 16 + kq];
            x[rr] = make_float4(a.x * b.x, a.y * b.y, a.z * b.z, a.w * b.w);
        }
#pragma unroll
        for (int kk = 0; kk < 4; kk++) {
            int k = 64 + kq * 4 + kk;
#pragma unroll
            for (int cq = 0; cq < 4; cq++) {
                float4 w = *(const float4*)&sW[k][c0 + cq * 4];
#pragma unroll
                for (int rr = 0; rr < 4; rr++) {
                    float xv = (&x[rr].x)[kk];
                    acc[rr][cq * 4 + 0] += xv * w.x;
                    acc[rr][cq * 4 + 1] += xv * w.y;
                    acc[rr][cq * 4 + 2] += xv * w.z;
                    acc[rr][cq * 4 + 3] += xv * w.w;
                }
            }
        }
    }

#pragma unroll
    for (int rr = 0; rr < 4; rr++) {
        float s = 0.f;
#pragma unroll
        for (int c = 0; c < 16; c++) {
            float v = acc[rr][c];
            v = v > 0.f ? v : 0.2f * v;
            acc[rr][c] = v;
            s += v * v;
        }
        s += __shfl_xor(s, 1, 64);
        s += __shfl_xor(s, 2, 64);
        float inv = 1.0f / fmaxf(sqrtf(s), 1e-12f);
        int row = r0 + rr;
        if (row < N) {
            float4* pe = (float4*)&ego[(size_t)row * EMB + c0];
            unsigned int pk[8], pn[8];
#pragma unroll
            for (int i = 0; i < 8; i++) {
                float e0 = acc[rr][2 * i], e1 = acc[rr][2 * i + 1];
                pk[i] = (unsigned int)f2b(e0) | ((unsigned int)f2b(e1) << 16);
                pn[i] = (unsigned int)f2b(e0 * inv) | ((unsigned int)f2b(e1 * inv) << 16);
            }
#pragma unroll
            for (int cq = 0; cq < 4; cq++)
                pe[cq] = make_float4(acc[rr][cq * 4 + 0], acc[rr][cq * 4 + 1],
                                     acc[rr][cq * 4 + 2], acc[rr][cq * 4 + 3]);
            uint4* pb = (uint4*)&egob[(size_t)row * EMB + c0];
            pb[0] = make_uint4(pk[0], pk[1], pk[2], pk[3]);
            pb[1] = make_uint4(pk[4], pk[5], pk[6], pk[7]);
            uint4* pa = (uint4*)&all_eb[(size_t)row * 256 + layer_col + c0];
            pa[0] = make_uint4(pn[0], pn[1], pn[2], pn[3]);
            pa[1] = make_uint4(pn[4], pn[5], pn[6], pn[7]);
        }
    }
}

// ---------------------------------------------------------------------------
// out(f32) = [all_eb[users], all_eb[nu+pos], all_eb[nu+neg]] (bf16 -> f32)
// ---------------------------------------------------------------------------
__global__ void k_gather(const unsigned short* __restrict__ all_eb,
                         const int* __restrict__ users,
                         const int* __restrict__ pos,
                         const int* __restrict__ neg,
                         float* __restrict__ out, int n_user, int batch) {
    int idx = blockIdx.x * blockDim.x + threadIdx.x;
    int total = batch * 256;
    if (idx >= 3 * total) return;
    int which = idx / total;
    int r = idx - which * total;
    int b = r >> 8;
    int c = r & 255;
    int node;
    if (which == 0) node = users[b];
    else if (which == 1) node = n_user + pos[b];
    else node = n_user + neg[b];
    out[idx] = b2f(all_eb[(size_t)node * 256 + c]);
}

static inline size_t align256(size_t x) { return (x + 255) & ~(size_t)255; }

extern "C" void kernel_launch(void* const* d_in, const int* in_sizes, int n_in,
                              void* d_out, int out_size, void* d_ws, size_t ws_size,
                              hipStream_t stream) {
    const float* user_emb = (const float*)d_in[0];
    const float* item_emb = (const float*)d_in[1];
    const float* W_gc = (const float*)d_in[2];
    const float* b_gc = (const float*)d_in[3];
    const float* W_bi = (const float*)d_in[4];
    const float* b_bi = (const float*)d_in[5];
    const int* edge_src = (const int*)d_in[7];
    const int* edge_dst = (const int*)d_in[8];
    const int* users = (const int*)d_in[9];
    const int* pos = (const int*)d_in[10];
    const int* neg = (const int*)d_in[11];

    int n_user = in_sizes[0] / EMB;
    int n_item = in_sizes[1] / EMB;
    int N = n_user + n_item;
    int M = in_sizes[6];
    int layers = in_sizes[2] / (EMB * EMB);
    int batch = in_sizes[9];
    float* out = (float*)d_out;

    int nblk = (N + 255) / 256;                  // scan blocks
    int nb2 = (N + B2ROWS - 1) >> B2SHIFT;       // 586 buckets

    // workspace carve (~206 MB — well inside proven budget)
    char* p = (char*)d_ws;
    float* ego = (float*)p;            p += align256((size_t)N * EMB * 4);
    unsigned short* egob = (unsigned short*)p;   p += align256((size_t)N * EMB * 2);
    float* side = (float*)p;           p += align256((size_t)N * EMB * 4);
    unsigned short* all_eb = (unsigned short*)p; p += align256((size_t)N * 256 * 2);
    int* counts = (int*)p;             p += align256((size_t)N * 4);       // -> dsq
    int* row_ptr = (int*)p;            p += align256((size_t)(N + 1) * 4);
    int* partial = (int*)p;            p += align256((size_t)nblk * 4);
    int* bcur = (int*)p;               p += align256((size_t)nb2 * 4);
    int* binned = (int*)p;             p += align256((size_t)M * 4);
    int* csr = (int*)p;                p += align256((size_t)M * 4);

    hipMemsetAsync(counts, 0, (size_t)N * 4, stream);

    k_init_ego<<<(N * EMB + 255) / 256, 256, 0, stream>>>(
        user_emb, item_emb, ego, egob, all_eb, n_user, N);

    // CSR build (once per launch; reused by all 3 layers)
    k_hist<<<(M + 255) / 256, 256, 0, stream>>>(edge_dst, counts, M);
    k_blocksum<<<nblk, 256, 0, stream>>>(counts, partial, N);
    k_scan_partials<<<1, 1024, 0, stream>>>(partial, nblk);
    k_rowptr<<<nblk, 256, 0, stream>>>(counts, partial, row_ptr, N);
    k_dsq<<<(N + 255) / 256, 256, 0, stream>>>(counts, N);   // counts -> dsq
    k_bcur<<<(nb2 + 255) / 256, 256, 0, stream>>>(row_ptr, bcur, nb2, N);
    k_bin<<<512, 256, 0, stream>>>(edge_src, edge_dst, bcur, binned, M, nb2);
    k_csrb<<<nb2, 256, 0, stream>>>(row_ptr, binned, csr, N);

    const float* dsq = (const float*)counts;
    for (int k = 0; k < layers; k++) {
        k_side<<<(N + 3) / 4, 256, 0, stream>>>(row_ptr, csr, dsq, egob, side, N);
        k_transform<<<(N + 255) / 256, 256, 0, stream>>>(
            side, ego, egob, W_gc + (size_t)k * EMB * EMB, b_gc + (size_t)k * EMB,
            W_bi + (size_t)k * EMB * EMB, b_bi + (size_t)k * EMB,
            all_eb, N, (k + 1) * EMB);
    }

    k_gather<<<(3 * batch * 256 + 255) / 256, 256, 0, stream>>>(
        all_eb, users, pos, neg, out, n_user, batch);
}

// Round 9
// 964.954 us; speedup vs baseline: 6.1088x; 1.1393x over previous
//
#include <hip/hip_runtime.h>

#define EMB 64
#define B2SHIFT 8                 // 256 dst rows per bucket
#define B2ROWS 256
#define MAXB 1024                 // LDS hist capacity (586 buckets actual)

__device__ __forceinline__ float b2f(unsigned short u) {
    return __uint_as_float(((unsigned int)u) << 16);
}
__device__ __forceinline__ unsigned short f2b(float f) {
    unsigned int u = __float_as_uint(f);
    u += 0x7FFF + ((u >> 16) & 1);          // round-to-nearest-even
    return (unsigned short)(u >> 16);
}

// ---------------------------------------------------------------------------
// ego = concat(user_emb, item_emb) (f32 + bf16 copies); all_e[:,0:64] = bf16
// ---------------------------------------------------------------------------
__global__ void k_init_ego(const float* __restrict__ user_emb,
                           const float* __restrict__ item_emb,
                           float* __restrict__ ego, unsigned short* __restrict__ egob,
                           unsigned short* __restrict__ all_eb,
                           int n_user, int N) {
    int idx = blockIdx.x * blockDim.x + threadIdx.x;
    int total = N * EMB;
    if (idx >= total) return;
    int n = idx >> 6;
    int c = idx & 63;
    float v = (n < n_user) ? user_emb[idx] : item_emb[(size_t)(n - n_user) * EMB + c];
    ego[idx] = v;
    unsigned short b = f2b(v);
    egob[idx] = b;
    all_eb[(size_t)n * 256 + c] = b;
}

// ---------------------------------------------------------------------------
// Bucket histogram (586 buckets): LDS pre-aggregation per block, then one
// global atomic per (block,bucket) — ~300K atomics total, not 4M.
// ---------------------------------------------------------------------------
__global__ __launch_bounds__(256) void k_bhist(const int* __restrict__ dst,
                                               int* __restrict__ bins,
                                               int M, int nb2) {
    __shared__ int h[MAXB];
    for (int i = threadIdx.x; i < nb2; i += 256) h[i] = 0;
    __syncthreads();
    for (int e = blockIdx.x * 256 + threadIdx.x; e < M; e += gridDim.x * 256)
        atomicAdd(&h[dst[e] >> B2SHIFT], 1);
    __syncthreads();
    for (int i = threadIdx.x; i < nb2; i += 256)
        if (h[i]) atomicAdd(&bins[i], h[i]);
}

// ---------------------------------------------------------------------------
// Exclusive scan of nb2 (<=1024) bins -> boff[0..P], bcur copy; row_ptr[N]=M
// ---------------------------------------------------------------------------
__global__ __launch_bounds__(1024) void k_bscan(const int* __restrict__ bins,
                                                int* __restrict__ boff,
                                                int* __restrict__ bcur,
                                                int* __restrict__ row_ptr,
                                                int P, int N) {
    __shared__ int buf[1024];
    int tid = threadIdx.x;
    int v = (tid < P) ? bins[tid] : 0;
    buf[tid] = v;
    __syncthreads();
    for (int d = 1; d < 1024; d <<= 1) {
        int add = (tid >= d) ? buf[tid - d] : 0;
        __syncthreads();
        buf[tid] += add;
        __syncthreads();
    }
    if (tid < P) {
        int excl = buf[tid] - v;
        boff[tid] = excl;
        bcur[tid] = excl;
    }
    if (tid == P - 1) {
        boff[P] = buf[tid];
        row_ptr[N] = buf[tid];
    }
}

// ---------------------------------------------------------------------------
// Multisplit pass 1: per-block LDS bucket histogram -> one global reservation
// per (block,bucket) -> append edges into block-private runs (single-writer
// => full lines assemble in one XCD's L2). entry = (src << 8) | (dst & 255)
// ---------------------------------------------------------------------------
__global__ __launch_bounds__(256) void k_bin(const int* __restrict__ src,
                                             const int* __restrict__ dst,
                                             int* __restrict__ bcur,
                                             int* __restrict__ binned,
                                             int M, int nb2) {
    __shared__ int hist[MAXB];
    __shared__ int runcur[MAXB];
    int chunk = (M + gridDim.x - 1) / gridDim.x;
    int lo = blockIdx.x * chunk;
    int hi = min(lo + chunk, M);
    for (int i = threadIdx.x; i < nb2; i += 256) hist[i] = 0;
    __syncthreads();
    for (int e = lo + threadIdx.x; e < hi; e += 256)
        atomicAdd(&hist[dst[e] >> B2SHIFT], 1);
    __syncthreads();
    for (int i = threadIdx.x; i < nb2; i += 256) {
        int c = hist[i];
        runcur[i] = c ? atomicAdd(&bcur[i], c) : 0;
    }
    __syncthreads();
    for (int e = lo + threadIdx.x; e < hi; e += 256) {
        int d = dst[e];
        int pos = atomicAdd(&runcur[d >> B2SHIFT], 1);
        binned[pos] = (src[e] << B2SHIFT) | (d & (B2ROWS - 1));
    }
}

// ---------------------------------------------------------------------------
// Multisplit pass 2 + CSR finalize: one block per bucket. LDS per-node
// histogram of the bucket's slice -> LDS scan -> row_ptr AND dsq (deg never
// materialized globally) -> scatter src into the bucket's ~27KB csr window.
// ---------------------------------------------------------------------------
__global__ __launch_bounds__(256) void k_csrb(const int* __restrict__ boff,
                                              const int* __restrict__ binned,
                                              int* __restrict__ row_ptr,
                                              float* __restrict__ dsq,
                                              int* __restrict__ csr, int N) {
    __shared__ int hist[B2ROWS];
    __shared__ int scan[B2ROWS];
    int b = blockIdx.x;
    int beg = boff[b], end = boff[b + 1];
    int tid = threadIdx.x;
    hist[tid] = 0;
    __syncthreads();
    for (int e = beg + tid; e < end; e += 256)
        atomicAdd(&hist[binned[e] & (B2ROWS - 1)], 1);
    __syncthreads();
    int c = hist[tid];
    scan[tid] = c;
    __syncthreads();
    for (int d = 1; d < B2ROWS; d <<= 1) {
        int add = (tid >= d) ? scan[tid - d] : 0;
        __syncthreads();
        scan[tid] += add;
        __syncthreads();
    }
    int excl = beg + scan[tid] - c;
    int node = (b << B2SHIFT) + tid;
    if (node < N) {
        row_ptr[node] = excl;
        dsq[node] = (c > 0) ? rsqrtf((float)c) : 0.0f;
    }
    __syncthreads();
    hist[tid] = excl;               // reuse as per-node cursor
    __syncthreads();
    for (int e = beg + tid; e < end; e += 256) {
        int v = binned[e];
        int pos = atomicAdd(&hist[v & (B2ROWS - 1)], 1);
        csr[pos] = v >> B2SHIFT;
    }
}

// ---------------------------------------------------------------------------
// side[n] = dsq[n] * sum dsq[src] * ego_bf16[src]  — one wave per node,
// lane = component, bf16 rows (128B/gather), 8 gathers in flight
// ---------------------------------------------------------------------------
__global__ __launch_bounds__(256) void k_side(const int* __restrict__ row_ptr,
                                              const int* __restrict__ csr,
                                              const float* __restrict__ dsq,
                                              const unsigned short* __restrict__ egob,
                                              float* __restrict__ side, int N) {
    int wave = threadIdx.x >> 6;
    int lane = threadIdx.x & 63;
    int n = blockIdx.x * 4 + wave;
    if (n >= N) return;
    int beg = row_ptr[n];
    int end = row_ptr[n + 1];
    float a0 = 0.f, a1 = 0.f, a2 = 0.f, a3 = 0.f;
    int e = beg;
    while ((e & 3) && e < end) {
        int s = csr[e];
        a0 += dsq[s] * b2f(egob[(size_t)s * EMB + lane]);
        e++;
    }
    for (; e + 8 <= end; e += 8) {
        int4 p = *(const int4*)(csr + e);
        int4 q = *(const int4*)(csr + e + 4);
        float v0 = b2f(egob[(size_t)p.x * EMB + lane]);
        float v1 = b2f(egob[(size_t)p.y * EMB + lane]);
        float v2 = b2f(egob[(size_t)p.z * EMB + lane]);
        float v3 = b2f(egob[(size_t)p.w * EMB + lane]);
        float v4 = b2f(egob[(size_t)q.x * EMB + lane]);
        float v5 = b2f(egob[(size_t)q.y * EMB + lane]);
        float v6 = b2f(egob[(size_t)q.z * EMB + lane]);
        float v7 = b2f(egob[(size_t)q.w * EMB + lane]);
        a0 += dsq[p.x] * v0;
        a1 += dsq[p.y] * v1;
        a2 += dsq[p.z] * v2;
        a3 += dsq[p.w] * v3;
        a0 += dsq[q.x] * v4;
        a1 += dsq[q.y] * v5;
        a2 += dsq[q.z] * v6;
        a3 += dsq[q.w] * v7;
    }
    for (; e + 4 <= end; e += 4) {
        int4 p = *(const int4*)(csr + e);
        a0 += dsq[p.x] * b2f(egob[(size_t)p.x * EMB + lane]);
        a1 += dsq[p.y] * b2f(egob[(size_t)p.y * EMB + lane]);
        a2 += dsq[p.z] * b2f(egob[(size_t)p.z * EMB + lane]);
        a3 += dsq[p.w] * b2f(egob[(size_t)p.w * EMB + lane]);
    }
    for (; e < end; e++) {
        int s = csr[e];
        a0 += dsq[s] * b2f(egob[(size_t)s * EMB + lane]);
    }
    side[(size_t)n * EMB + lane] = dsq[n] * ((a0 + a1) + (a2 + a3));
}

// ---------------------------------------------------------------------------
// Fused transform: out = leaky_relu(side@Wgc + bgc + (ego*side)@Wbi + bbi)
// ego(f32) <- out; egob(bf16) <- out; all_eb[:,col] <- bf16(out/||out||)
// ---------------------------------------------------------------------------
__global__ __launch_bounds__(256) void k_transform(
        const float* __restrict__ side, float* __restrict__ ego,
        unsigned short* __restrict__ egob,
        const float* __restrict__ Wgc, const float* __restrict__ bgc,
        const float* __restrict__ Wbi, const float* __restrict__ bbi,
        unsigned short* __restrict__ all_eb, int N, int layer_col) {
    __shared__ float sW[128][64];
    __shared__ float sB[64];
    int tid = threadIdx.x;
    for (int i = tid; i < 64 * 64; i += 256) {
        sW[i >> 6][i & 63] = Wgc[i];
        sW[64 + (i >> 6)][i & 63] = Wbi[i];
    }
    if (tid < 64) sB[tid] = bgc[tid] + bbi[tid];
    __syncthreads();

    int cg = tid & 3;
    int rg = tid >> 2;
    int c0 = cg * 16;
    int r0 = blockIdx.x * 256 + rg * 4;

    float acc[4][16];
#pragma unroll
    for (int rr = 0; rr < 4; rr++)
#pragma unroll
        for (int c = 0; c < 16; c++) acc[rr][c] = sB[c0 + c];

    int ri[4];
#pragma unroll
    for (int rr = 0; rr < 4; rr++) ri[rr] = min(r0 + rr, N - 1);

    const float4* side4 = (const float4*)side;
    const float4* ego4 = (const float4*)ego;

#pragma unroll 1
    for (int kq = 0; kq < 16; kq++) {
        float4 x[4];
#pragma unroll
        for (int rr = 0; rr < 4; rr++) x[rr] = side4[(size_t)ri[rr] * 16 + kq];
#pragma unroll
        for (int kk = 0; kk < 4; kk++) {
            int k = kq * 4 + kk;
#pragma unroll
            for (int cq = 0; cq < 4; cq++) {
                float4 w = *(const float4*)&sW[k][c0 + cq * 4];
#pragma unroll
                for (int rr = 0; rr < 4; rr++) {
                    float xv = (&x[rr].x)[kk];
                    acc[rr][cq * 4 + 0] += xv * w.x;
                    acc[rr][cq * 4 + 1] += xv * w.y;
                    acc[rr][cq * 4 + 2] += xv * w.z;
                    acc[rr][cq * 4 + 3] += xv * w.w;
                }
            }
        }
    }

#pragma unroll 1
    for (int kq = 0; kq < 16; kq++) {
        float4 x[4];
#pragma unroll
        for (int rr = 0; rr < 4; rr++) {
            float4 a = ego4[(size_t)ri[rr] * 16 + kq];
            float4 b = side4[(size_t)ri[rr] * 16 + kq];
            x[rr] = make_float4(a.x * b.x, a.y * b.y, a.z * b.z, a.w * b.w);
        }
#pragma unroll
        for (int kk = 0; kk < 4; kk++) {
            int k = 64 + kq * 4 + kk;
#pragma unroll
            for (int cq = 0; cq < 4; cq++) {
                float4 w = *(const float4*)&sW[k][c0 + cq * 4];
#pragma unroll
                for (int rr = 0; rr < 4; rr++) {
                    float xv = (&x[rr].x)[kk];
                    acc[rr][cq * 4 + 0] += xv * w.x;
                    acc[rr][cq * 4 + 1] += xv * w.y;
                    acc[rr][cq * 4 + 2] += xv * w.z;
                    acc[rr][cq * 4 + 3] += xv * w.w;
                }
            }
        }
    }

#pragma unroll
    for (int rr = 0; rr < 4; rr++) {
        float s = 0.f;
#pragma unroll
        for (int c = 0; c < 16; c++) {
            float v = acc[rr][c];
            v = v > 0.f ? v : 0.2f * v;
            acc[rr][c] = v;
            s += v * v;
        }
        s += __shfl_xor(s, 1, 64);
        s += __shfl_xor(s, 2, 64);
        float inv = 1.0f / fmaxf(sqrtf(s), 1e-12f);
        int row = r0 + rr;
        if (row < N) {
            float4* pe = (float4*)&ego[(size_t)row * EMB + c0];
            unsigned int pk[8], pn[8];
#pragma unroll
            for (int i = 0; i < 8; i++) {
                float e0 = acc[rr][2 * i], e1 = acc[rr][2 * i + 1];
                pk[i] = (unsigned int)f2b(e0) | ((unsigned int)f2b(e1) << 16);
                pn[i] = (unsigned int)f2b(e0 * inv) | ((unsigned int)f2b(e1 * inv) << 16);
            }
#pragma unroll
            for (int cq = 0; cq < 4; cq++)
                pe[cq] = make_float4(acc[rr][cq * 4 + 0], acc[rr][cq * 4 + 1],
                                     acc[rr][cq * 4 + 2], acc[rr][cq * 4 + 3]);
            uint4* pb = (uint4*)&egob[(size_t)row * EMB + c0];
            pb[0] = make_uint4(pk[0], pk[1], pk[2], pk[3]);
            pb[1] = make_uint4(pk[4], pk[5], pk[6], pk[7]);
            uint4* pa = (uint4*)&all_eb[(size_t)row * 256 + layer_col + c0];
            pa[0] = make_uint4(pn[0], pn[1], pn[2], pn[3]);
            pa[1] = make_uint4(pn[4], pn[5], pn[6], pn[7]);
        }
    }
}

// ---------------------------------------------------------------------------
// out(f32) = [all_eb[users], all_eb[nu+pos], all_eb[nu+neg]] (bf16 -> f32)
// ---------------------------------------------------------------------------
__global__ void k_gather(const unsigned short* __restrict__ all_eb,
                         const int* __restrict__ users,
                         const int* __restrict__ pos,
                         const int* __restrict__ neg,
                         float* __restrict__ out, int n_user, int batch) {
    int idx = blockIdx.x * blockDim.x + threadIdx.x;
    int total = batch * 256;
    if (idx >= 3 * total) return;
    int which = idx / total;
    int r = idx - which * total;
    int b = r >> 8;
    int c = r & 255;
    int node;
    if (which == 0) node = users[b];
    else if (which == 1) node = n_user + pos[b];
    else node = n_user + neg[b];
    out[idx] = b2f(all_eb[(size_t)node * 256 + c]);
}

static inline size_t align256(size_t x) { return (x + 255) & ~(size_t)255; }

extern "C" void kernel_launch(void* const* d_in, const int* in_sizes, int n_in,
                              void* d_out, int out_size, void* d_ws, size_t ws_size,
                              hipStream_t stream) {
    const float* user_emb = (const float*)d_in[0];
    const float* item_emb = (const float*)d_in[1];
    const float* W_gc = (const float*)d_in[2];
    const float* b_gc = (const float*)d_in[3];
    const float* W_bi = (const float*)d_in[4];
    const float* b_bi = (const float*)d_in[5];
    const int* edge_src = (const int*)d_in[7];
    const int* edge_dst = (const int*)d_in[8];
    const int* users = (const int*)d_in[9];
    const int* pos = (const int*)d_in[10];
    const int* neg = (const int*)d_in[11];

    int n_user = in_sizes[0] / EMB;
    int n_item = in_sizes[1] / EMB;
    int N = n_user + n_item;
    int M = in_sizes[6];
    int layers = in_sizes[2] / (EMB * EMB);
    int batch = in_sizes[9];
    float* out = (float*)d_out;

    int nb2 = (N + B2ROWS - 1) >> B2SHIFT;       // 586 buckets

    // workspace carve (~206 MB — well inside proven budget)
    char* p = (char*)d_ws;
    float* ego = (float*)p;            p += align256((size_t)N * EMB * 4);
    unsigned short* egob = (unsigned short*)p;   p += align256((size_t)N * EMB * 2);
    float* side = (float*)p;           p += align256((size_t)N * EMB * 4);
    unsigned short* all_eb = (unsigned short*)p; p += align256((size_t)N * 256 * 2);
    float* dsq = (float*)p;            p += align256((size_t)N * 4);
    int* row_ptr = (int*)p;            p += align256((size_t)(N + 1) * 4);
    int* bins = (int*)p;               p += align256((size_t)nb2 * 4);
    int* boff = (int*)p;               p += align256((size_t)(nb2 + 1) * 4);
    int* bcur = (int*)p;               p += align256((size_t)nb2 * 4);
    int* binned = (int*)p;             p += align256((size_t)M * 4);
    int* csr = (int*)p;                p += align256((size_t)M * 4);

    hipMemsetAsync(bins, 0, (size_t)nb2 * 4, stream);   // 2.3 KB

    k_init_ego<<<(N * EMB + 255) / 256, 256, 0, stream>>>(
        user_emb, item_emb, ego, egob, all_eb, n_user, N);

    // bucket-first CSR build (once per launch; reused by all 3 layers)
    k_bhist<<<512, 256, 0, stream>>>(edge_dst, bins, M, nb2);
    k_bscan<<<1, 1024, 0, stream>>>(bins, boff, bcur, row_ptr, nb2, N);
    k_bin<<<512, 256, 0, stream>>>(edge_src, edge_dst, bcur, binned, M, nb2);
    k_csrb<<<nb2, 256, 0, stream>>>(boff, binned, row_ptr, dsq, csr, N);

    for (int k = 0; k < layers; k++) {
        k_side<<<(N + 3) / 4, 256, 0, stream>>>(row_ptr, csr, dsq, egob, side, N);
        k_transform<<<(N + 255) / 256, 256, 0, stream>>>(
            side, ego, egob, W_gc + (size_t)k * EMB * EMB, b_gc + (size_t)k * EMB,
            W_bi + (size_t)k * EMB * EMB, b_bi + (size_t)k * EMB,
            all_eb, N, (k + 1) * EMB);
    }

    k_gather<<<(3 * batch * 256 + 255) / 256, 256, 0, stream>>>(
        all_eb, users, pos, neg, out, n_user, batch);
}

// Round 10
// 893.808 us; speedup vs baseline: 6.5950x; 1.0796x over previous
//
#include <hip/hip_runtime.h>

#define EMB 64
#define B2SHIFT 8                 // 256 dst rows per bucket
#define B2ROWS 256
#define MAXB 1024                 // LDS hist capacity (586 buckets actual)

__device__ __forceinline__ float b2f(unsigned short u) {
    return __uint_as_float(((unsigned int)u) << 16);
}
__device__ __forceinline__ unsigned short f2b(float f) {
    unsigned int u = __float_as_uint(f);
    u += 0x7FFF + ((u >> 16) & 1);          // round-to-nearest-even
    return (unsigned short)(u >> 16);
}

// ---------------------------------------------------------------------------
// init (runs AFTER csr build so dsq is available):
// egob = bf16(ego); egow = bf16(dsq[n]*ego); all_eb[:,0:64] = bf16(ego)
// ---------------------------------------------------------------------------
__global__ void k_init_ego(const float* __restrict__ user_emb,
                           const float* __restrict__ item_emb,
                           const float* __restrict__ dsq,
                           unsigned short* __restrict__ egob,
                           unsigned short* __restrict__ egow,
                           unsigned short* __restrict__ all_eb,
                           int n_user, int N) {
    int idx = blockIdx.x * blockDim.x + threadIdx.x;
    int total = N * EMB;
    if (idx >= total) return;
    int n = idx >> 6;
    int c = idx & 63;
    float v = (n < n_user) ? user_emb[idx] : item_emb[(size_t)(n - n_user) * EMB + c];
    unsigned short b = f2b(v);
    egob[idx] = b;
    egow[idx] = f2b(dsq[n] * v);
    all_eb[(size_t)n * 256 + c] = b;
}

// ---------------------------------------------------------------------------
// Bucket histogram (586 buckets): LDS pre-aggregation, ~300K global atomics
// ---------------------------------------------------------------------------
__global__ __launch_bounds__(256) void k_bhist(const int* __restrict__ dst,
                                               int* __restrict__ bins,
                                               int M, int nb2) {
    __shared__ int h[MAXB];
    for (int i = threadIdx.x; i < nb2; i += 256) h[i] = 0;
    __syncthreads();
    for (int e = blockIdx.x * 256 + threadIdx.x; e < M; e += gridDim.x * 256)
        atomicAdd(&h[dst[e] >> B2SHIFT], 1);
    __syncthreads();
    for (int i = threadIdx.x; i < nb2; i += 256)
        if (h[i]) atomicAdd(&bins[i], h[i]);
}

// ---------------------------------------------------------------------------
// Exclusive scan of nb2 (<=1024) bins -> boff[0..P], bcur copy; row_ptr[N]=M
// ---------------------------------------------------------------------------
__global__ __launch_bounds__(1024) void k_bscan(const int* __restrict__ bins,
                                                int* __restrict__ boff,
                                                int* __restrict__ bcur,
                                                int* __restrict__ row_ptr,
                                                int P, int N) {
    __shared__ int buf[1024];
    int tid = threadIdx.x;
    int v = (tid < P) ? bins[tid] : 0;
    buf[tid] = v;
    __syncthreads();
    for (int d = 1; d < 1024; d <<= 1) {
        int add = (tid >= d) ? buf[tid - d] : 0;
        __syncthreads();
        buf[tid] += add;
        __syncthreads();
    }
    if (tid < P) {
        int excl = buf[tid] - v;
        boff[tid] = excl;
        bcur[tid] = excl;
    }
    if (tid == P - 1) {
        boff[P] = buf[tid];
        row_ptr[N] = buf[tid];
    }
}

// ---------------------------------------------------------------------------
// Multisplit pass 1: block-private runs per bucket (single-writer lines)
// entry = (src << 8) | (dst & 255)
// ---------------------------------------------------------------------------
__global__ __launch_bounds__(256) void k_bin(const int* __restrict__ src,
                                             const int* __restrict__ dst,
                                             int* __restrict__ bcur,
                                             int* __restrict__ binned,
                                             int M, int nb2) {
    __shared__ int hist[MAXB];
    __shared__ int runcur[MAXB];
    int chunk = (M + gridDim.x - 1) / gridDim.x;
    int lo = blockIdx.x * chunk;
    int hi = min(lo + chunk, M);
    for (int i = threadIdx.x; i < nb2; i += 256) hist[i] = 0;
    __syncthreads();
    for (int e = lo + threadIdx.x; e < hi; e += 256)
        atomicAdd(&hist[dst[e] >> B2SHIFT], 1);
    __syncthreads();
    for (int i = threadIdx.x; i < nb2; i += 256) {
        int c = hist[i];
        runcur[i] = c ? atomicAdd(&bcur[i], c) : 0;
    }
    __syncthreads();
    for (int e = lo + threadIdx.x; e < hi; e += 256) {
        int d = dst[e];
        int pos = atomicAdd(&runcur[d >> B2SHIFT], 1);
        binned[pos] = (src[e] << B2SHIFT) | (d & (B2ROWS - 1));
    }
}

// ---------------------------------------------------------------------------
// Multisplit pass 2 + CSR finalize (also produces row_ptr and dsq)
// ---------------------------------------------------------------------------
__global__ __launch_bounds__(256) void k_csrb(const int* __restrict__ boff,
                                              const int* __restrict__ binned,
                                              int* __restrict__ row_ptr,
                                              float* __restrict__ dsq,
                                              int* __restrict__ csr, int N) {
    __shared__ int hist[B2ROWS];
    __shared__ int scan[B2ROWS];
    int b = blockIdx.x;
    int beg = boff[b], end = boff[b + 1];
    int tid = threadIdx.x;
    hist[tid] = 0;
    __syncthreads();
    for (int e = beg + tid; e < end; e += 256)
        atomicAdd(&hist[binned[e] & (B2ROWS - 1)], 1);
    __syncthreads();
    int c = hist[tid];
    scan[tid] = c;
    __syncthreads();
    for (int d = 1; d < B2ROWS; d <<= 1) {
        int add = (tid >= d) ? scan[tid - d] : 0;
        __syncthreads();
        scan[tid] += add;
        __syncthreads();
    }
    int excl = beg + scan[tid] - c;
    int node = (b << B2SHIFT) + tid;
    if (node < N) {
        row_ptr[node] = excl;
        dsq[node] = (c > 0) ? rsqrtf((float)c) : 0.0f;
    }
    __syncthreads();
    hist[tid] = excl;               // reuse as per-node cursor
    __syncthreads();
    for (int e = beg + tid; e < end; e += 256) {
        int v = binned[e];
        int pos = atomicAdd(&hist[v & (B2ROWS - 1)], 1);
        csr[pos] = v >> B2SHIFT;
    }
}

// ---------------------------------------------------------------------------
// side[n] = dsq[n] * sum egow[src]  — one wave per node, lane = component.
// readfirstlane makes the edge loop wave-uniform: csr reads become s_load,
// row base becomes SGPR => gathers are saddr-form ushort loads (lane only).
// Vector-memory instrs per 8 edges: 8 (was 18).
// ---------------------------------------------------------------------------
__global__ __launch_bounds__(256) void k_side(const int* __restrict__ row_ptr,
                                              const int* __restrict__ csr,
                                              const float* __restrict__ dsq,
                                              const unsigned short* __restrict__ egow,
                                              float* __restrict__ side, int N) {
    int wave = threadIdx.x >> 6;
    int lane = threadIdx.x & 63;
    int n = blockIdx.x * 4 + wave;
    if (n >= N) return;
    int beg = __builtin_amdgcn_readfirstlane(row_ptr[n]);
    int end = __builtin_amdgcn_readfirstlane(row_ptr[n + 1]);
    float a0 = 0.f, a1 = 0.f, a2 = 0.f, a3 = 0.f;
    int e = beg;
    for (; e + 8 <= end; e += 8) {
        int s0 = __builtin_amdgcn_readfirstlane(csr[e + 0]);
        int s1 = __builtin_amdgcn_readfirstlane(csr[e + 1]);
        int s2 = __builtin_amdgcn_readfirstlane(csr[e + 2]);
        int s3 = __builtin_amdgcn_readfirstlane(csr[e + 3]);
        int s4 = __builtin_amdgcn_readfirstlane(csr[e + 4]);
        int s5 = __builtin_amdgcn_readfirstlane(csr[e + 5]);
        int s6 = __builtin_amdgcn_readfirstlane(csr[e + 6]);
        int s7 = __builtin_amdgcn_readfirstlane(csr[e + 7]);
        float v0 = b2f(egow[(size_t)s0 * EMB + lane]);
        float v1 = b2f(egow[(size_t)s1 * EMB + lane]);
        float v2 = b2f(egow[(size_t)s2 * EMB + lane]);
        float v3 = b2f(egow[(size_t)s3 * EMB + lane]);
        float v4 = b2f(egow[(size_t)s4 * EMB + lane]);
        float v5 = b2f(egow[(size_t)s5 * EMB + lane]);
        float v6 = b2f(egow[(size_t)s6 * EMB + lane]);
        float v7 = b2f(egow[(size_t)s7 * EMB + lane]);
        a0 += v0 + v4;
        a1 += v1 + v5;
        a2 += v2 + v6;
        a3 += v3 + v7;
    }
    for (; e < end; e++) {
        int s = __builtin_amdgcn_readfirstlane(csr[e]);
        a0 += b2f(egow[(size_t)s * EMB + lane]);
    }
    side[(size_t)n * EMB + lane] = dsq[n] * ((a0 + a1) + (a2 + a3));
}

// ---------------------------------------------------------------------------
// Fused transform: out = leaky_relu(side@Wgc + bgc + (ego*side)@Wbi + bbi)
// single k-loop (side read once); ego read as bf16 (egob); epilogue writes
// egob (bf16 out), egow (bf16 dsq*out), all_eb (bf16 normalized out).
// ---------------------------------------------------------------------------
__global__ __launch_bounds__(256) void k_transform(
        const float* __restrict__ side,
        unsigned short* __restrict__ egob, unsigned short* __restrict__ egow,
        const float* __restrict__ dsq,
        const float* __restrict__ Wgc, const float* __restrict__ bgc,
        const float* __restrict__ Wbi, const float* __restrict__ bbi,
        unsigned short* __restrict__ all_eb, int N, int layer_col) {
    __shared__ float sW[128][64];   // 0-63: Wgc, 64-127: Wbi
    __shared__ float sB[64];
    int tid = threadIdx.x;
    for (int i = tid; i < 64 * 64; i += 256) {
        sW[i >> 6][i & 63] = Wgc[i];
        sW[64 + (i >> 6)][i & 63] = Wbi[i];
    }
    if (tid < 64) sB[tid] = bgc[tid] + bbi[tid];
    __syncthreads();

    int cg = tid & 3;
    int rg = tid >> 2;
    int c0 = cg * 16;
    int r0 = blockIdx.x * 256 + rg * 4;

    float acc[4][16];
#pragma unroll
    for (int rr = 0; rr < 4; rr++)
#pragma unroll
        for (int c = 0; c < 16; c++) acc[rr][c] = sB[c0 + c];

    int ri[4];
#pragma unroll
    for (int rr = 0; rr < 4; rr++) ri[rr] = min(r0 + rr, N - 1);

    const float4* side4 = (const float4*)side;
    const uint2* egob2 = (const uint2*)egob;

#pragma unroll 1
    for (int kq = 0; kq < 16; kq++) {
        float4 xs[4], xb[4];
#pragma unroll
        for (int rr = 0; rr < 4; rr++) {
            float4 b = side4[(size_t)ri[rr] * 16 + kq];
            uint2 ab = egob2[(size_t)ri[rr] * 16 + kq];
            float e0 = __uint_as_float(ab.x << 16);
            float e1 = __uint_as_float(ab.x & 0xffff0000u);
            float e2 = __uint_as_float(ab.y << 16);
            float e3 = __uint_as_float(ab.y & 0xffff0000u);
            xs[rr] = b;
            xb[rr] = make_float4(e0 * b.x, e1 * b.y, e2 * b.z, e3 * b.w);
        }
#pragma unroll
        for (int kk = 0; kk < 4; kk++) {
            int k = kq * 4 + kk;
#pragma unroll
            for (int cq = 0; cq < 4; cq++) {
                float4 wg = *(const float4*)&sW[k][c0 + cq * 4];
                float4 wb = *(const float4*)&sW[64 + k][c0 + cq * 4];
#pragma unroll
                for (int rr = 0; rr < 4; rr++) {
                    float xg = (&xs[rr].x)[kk];
                    float xv = (&xb[rr].x)[kk];
                    acc[rr][cq * 4 + 0] += xg * wg.x + xv * wb.x;
                    acc[rr][cq * 4 + 1] += xg * wg.y + xv * wb.y;
                    acc[rr][cq * 4 + 2] += xg * wg.z + xv * wb.z;
                    acc[rr][cq * 4 + 3] += xg * wg.w + xv * wb.w;
                }
            }
        }
    }

#pragma unroll
    for (int rr = 0; rr < 4; rr++) {
        float s = 0.f;
#pragma unroll
        for (int c = 0; c < 16; c++) {
            float v = acc[rr][c];
            v = v > 0.f ? v : 0.2f * v;
            acc[rr][c] = v;
            s += v * v;
        }
        s += __shfl_xor(s, 1, 64);
        s += __shfl_xor(s, 2, 64);
        float inv = 1.0f / fmaxf(sqrtf(s), 1e-12f);
        int row = r0 + rr;
        if (row < N) {
            float dn = dsq[row];
            unsigned int pk[8], pw[8], pn[8];
#pragma unroll
            for (int i = 0; i < 8; i++) {
                float e0 = acc[rr][2 * i], e1 = acc[rr][2 * i + 1];
                pk[i] = (unsigned int)f2b(e0) | ((unsigned int)f2b(e1) << 16);
                pw[i] = (unsigned int)f2b(e0 * dn) | ((unsigned int)f2b(e1 * dn) << 16);
                pn[i] = (unsigned int)f2b(e0 * inv) | ((unsigned int)f2b(e1 * inv) << 16);
            }
            uint4* pb = (uint4*)&egob[(size_t)row * EMB + c0];
            pb[0] = make_uint4(pk[0], pk[1], pk[2], pk[3]);
            pb[1] = make_uint4(pk[4], pk[5], pk[6], pk[7]);
            uint4* pww = (uint4*)&egow[(size_t)row * EMB + c0];
            pww[0] = make_uint4(pw[0], pw[1], pw[2], pw[3]);
            pww[1] = make_uint4(pw[4], pw[5], pw[6], pw[7]);
            uint4* pa = (uint4*)&all_eb[(size_t)row * 256 + layer_col + c0];
            pa[0] = make_uint4(pn[0], pn[1], pn[2], pn[3]);
            pa[1] = make_uint4(pn[4], pn[5], pn[6], pn[7]);
        }
    }
}

// ---------------------------------------------------------------------------
// out(f32) = [all_eb[users], all_eb[nu+pos], all_eb[nu+neg]] (bf16 -> f32)
// ---------------------------------------------------------------------------
__global__ void k_gather(const unsigned short* __restrict__ all_eb,
                         const int* __restrict__ users,
                         const int* __restrict__ pos,
                         const int* __restrict__ neg,
                         float* __restrict__ out, int n_user, int batch) {
    int idx = blockIdx.x * blockDim.x + threadIdx.x;
    int total = batch * 256;
    if (idx >= 3 * total) return;
    int which = idx / total;
    int r = idx - which * total;
    int b = r >> 8;
    int c = r & 255;
    int node;
    if (which == 0) node = users[b];
    else if (which == 1) node = n_user + pos[b];
    else node = n_user + neg[b];
    out[idx] = b2f(all_eb[(size_t)node * 256 + c]);
}

static inline size_t align256(size_t x) { return (x + 255) & ~(size_t)255; }

extern "C" void kernel_launch(void* const* d_in, const int* in_sizes, int n_in,
                              void* d_out, int out_size, void* d_ws, size_t ws_size,
                              hipStream_t stream) {
    const float* user_emb = (const float*)d_in[0];
    const float* item_emb = (const float*)d_in[1];
    const float* W_gc = (const float*)d_in[2];
    const float* b_gc = (const float*)d_in[3];
    const float* W_bi = (const float*)d_in[4];
    const float* b_bi = (const float*)d_in[5];
    const int* edge_src = (const int*)d_in[7];
    const int* edge_dst = (const int*)d_in[8];
    const int* users = (const int*)d_in[9];
    const int* pos = (const int*)d_in[10];
    const int* neg = (const int*)d_in[11];

    int n_user = in_sizes[0] / EMB;
    int n_item = in_sizes[1] / EMB;
    int N = n_user + n_item;
    int M = in_sizes[6];
    int layers = in_sizes[2] / (EMB * EMB);
    int batch = in_sizes[9];
    float* out = (float*)d_out;

    int nb2 = (N + B2ROWS - 1) >> B2SHIFT;       // 586 buckets

    // workspace carve (~187 MB)
    char* p = (char*)d_ws;
    unsigned short* egob = (unsigned short*)p;   p += align256((size_t)N * EMB * 2);
    unsigned short* egow = (unsigned short*)p;   p += align256((size_t)N * EMB * 2);
    float* side = (float*)p;           p += align256((size_t)N * EMB * 4);
    unsigned short* all_eb = (unsigned short*)p; p += align256((size_t)N * 256 * 2);
    float* dsq = (float*)p;            p += align256((size_t)N * 4);
    int* row_ptr = (int*)p;            p += align256((size_t)(N + 1) * 4);
    int* bins = (int*)p;               p += align256((size_t)nb2 * 4);
    int* boff = (int*)p;               p += align256((size_t)(nb2 + 1) * 4);
    int* bcur = (int*)p;               p += align256((size_t)nb2 * 4);
    int* binned = (int*)p;             p += align256((size_t)M * 4);
    int* csr = (int*)p;                p += align256((size_t)M * 4);

    hipMemsetAsync(bins, 0, (size_t)nb2 * 4, stream);   // 2.3 KB

    // bucket-first CSR build (produces row_ptr, dsq, csr)
    k_bhist<<<512, 256, 0, stream>>>(edge_dst, bins, M, nb2);
    k_bscan<<<1, 1024, 0, stream>>>(bins, boff, bcur, row_ptr, nb2, N);
    k_bin<<<512, 256, 0, stream>>>(edge_src, edge_dst, bcur, binned, M, nb2);
    k_csrb<<<nb2, 256, 0, stream>>>(boff, binned, row_ptr, dsq, csr, N);

    // init AFTER csrb (needs dsq for the pre-scaled gather table)
    k_init_ego<<<(N * EMB + 255) / 256, 256, 0, stream>>>(
        user_emb, item_emb, dsq, egob, egow, all_eb, n_user, N);

    for (int k = 0; k < layers; k++) {
        k_side<<<(N + 3) / 4, 256, 0, stream>>>(row_ptr, csr, dsq, egow, side, N);
        k_transform<<<(N + 255) / 256, 256, 0, stream>>>(
            side, egob, egow, dsq,
            W_gc + (size_t)k * EMB * EMB, b_gc + (size_t)k * EMB,
            W_bi + (size_t)k * EMB * EMB, b_bi + (size_t)k * EMB,
            all_eb, N, (k + 1) * EMB);
    }

    k_gather<<<(3 * batch * 256 + 255) / 256, 256, 0, stream>>>(
        all_eb, users, pos, neg, out, n_user, batch);
}

// Round 11
// 622.400 us; speedup vs baseline: 9.4709x; 1.4361x over previous
//
#include <hip/hip_runtime.h>

#define EMB 64
#define B2SHIFT 8                 // 256 dst rows per bucket
#define B2ROWS 256
#define MAXB 1024                 // LDS hist capacity (586 buckets actual)

typedef short v8s __attribute__((ext_vector_type(8)));
typedef float v4f __attribute__((ext_vector_type(4)));

__device__ __forceinline__ float b2f(unsigned short u) {
    return __uint_as_float(((unsigned int)u) << 16);
}
__device__ __forceinline__ unsigned short f2b(float f) {
    unsigned int u = __float_as_uint(f);
    u += 0x7FFF + ((u >> 16) & 1);          // round-to-nearest-even
    return (unsigned short)(u >> 16);
}

// ---------------------------------------------------------------------------
// init (runs AFTER csr build so dsq is available):
// egob = bf16(ego); egow = bf16(dsq[n]*ego); all_eb[:,0:64] = bf16(ego)
// ---------------------------------------------------------------------------
__global__ void k_init_ego(const float* __restrict__ user_emb,
                           const float* __restrict__ item_emb,
                           const float* __restrict__ dsq,
                           unsigned short* __restrict__ egob,
                           unsigned short* __restrict__ egow,
                           unsigned short* __restrict__ all_eb,
                           int n_user, int N) {
    int idx = blockIdx.x * blockDim.x + threadIdx.x;
    int total = N * EMB;
    if (idx >= total) return;
    int n = idx >> 6;
    int c = idx & 63;
    float v = (n < n_user) ? user_emb[idx] : item_emb[(size_t)(n - n_user) * EMB + c];
    unsigned short b = f2b(v);
    egob[idx] = b;
    egow[idx] = f2b(dsq[n] * v);
    all_eb[(size_t)n * 256 + c] = b;
}

// ---------------------------------------------------------------------------
// Bucket histogram (586 buckets): LDS pre-aggregation, ~300K global atomics
// ---------------------------------------------------------------------------
__global__ __launch_bounds__(256) void k_bhist(const int* __restrict__ dst,
                                               int* __restrict__ bins,
                                               int M, int nb2) {
    __shared__ int h[MAXB];
    for (int i = threadIdx.x; i < nb2; i += 256) h[i] = 0;
    __syncthreads();
    for (int e = blockIdx.x * 256 + threadIdx.x; e < M; e += gridDim.x * 256)
        atomicAdd(&h[dst[e] >> B2SHIFT], 1);
    __syncthreads();
    for (int i = threadIdx.x; i < nb2; i += 256)
        if (h[i]) atomicAdd(&bins[i], h[i]);
}

// ---------------------------------------------------------------------------
// Exclusive scan of nb2 (<=1024) bins -> boff[0..P], bcur copy; row_ptr[N]=M
// ---------------------------------------------------------------------------
__global__ __launch_bounds__(1024) void k_bscan(const int* __restrict__ bins,
                                                int* __restrict__ boff,
                                                int* __restrict__ bcur,
                                                int* __restrict__ row_ptr,
                                                int P, int N) {
    __shared__ int buf[1024];
    int tid = threadIdx.x;
    int v = (tid < P) ? bins[tid] : 0;
    buf[tid] = v;
    __syncthreads();
    for (int d = 1; d < 1024; d <<= 1) {
        int add = (tid >= d) ? buf[tid - d] : 0;
        __syncthreads();
        buf[tid] += add;
        __syncthreads();
    }
    if (tid < P) {
        int excl = buf[tid] - v;
        boff[tid] = excl;
        bcur[tid] = excl;
    }
    if (tid == P - 1) {
        boff[P] = buf[tid];
        row_ptr[N] = buf[tid];
    }
}

// ---------------------------------------------------------------------------
// Multisplit pass 1: block-private runs per bucket (single-writer lines)
// entry = (src << 8) | (dst & 255)
// ---------------------------------------------------------------------------
__global__ __launch_bounds__(256) void k_bin(const int* __restrict__ src,
                                             const int* __restrict__ dst,
                                             int* __restrict__ bcur,
                                             int* __restrict__ binned,
                                             int M, int nb2) {
    __shared__ int hist[MAXB];
    __shared__ int runcur[MAXB];
    int chunk = (M + gridDim.x - 1) / gridDim.x;
    int lo = blockIdx.x * chunk;
    int hi = min(lo + chunk, M);
    for (int i = threadIdx.x; i < nb2; i += 256) hist[i] = 0;
    __syncthreads();
    for (int e = lo + threadIdx.x; e < hi; e += 256)
        atomicAdd(&hist[dst[e] >> B2SHIFT], 1);
    __syncthreads();
    for (int i = threadIdx.x; i < nb2; i += 256) {
        int c = hist[i];
        runcur[i] = c ? atomicAdd(&bcur[i], c) : 0;
    }
    __syncthreads();
    for (int e = lo + threadIdx.x; e < hi; e += 256) {
        int d = dst[e];
        int pos = atomicAdd(&runcur[d >> B2SHIFT], 1);
        binned[pos] = (src[e] << B2SHIFT) | (d & (B2ROWS - 1));
    }
}

// ---------------------------------------------------------------------------
// Multisplit pass 2 + CSR finalize (also produces row_ptr and dsq)
// ---------------------------------------------------------------------------
__global__ __launch_bounds__(256) void k_csrb(const int* __restrict__ boff,
                                              const int* __restrict__ binned,
                                              int* __restrict__ row_ptr,
                                              float* __restrict__ dsq,
                                              int* __restrict__ csr, int N) {
    __shared__ int hist[B2ROWS];
    __shared__ int scan[B2ROWS];
    int b = blockIdx.x;
    int beg = boff[b], end = boff[b + 1];
    int tid = threadIdx.x;
    hist[tid] = 0;
    __syncthreads();
    for (int e = beg + tid; e < end; e += 256)
        atomicAdd(&hist[binned[e] & (B2ROWS - 1)], 1);
    __syncthreads();
    int c = hist[tid];
    scan[tid] = c;
    __syncthreads();
    for (int d = 1; d < B2ROWS; d <<= 1) {
        int add = (tid >= d) ? scan[tid - d] : 0;
        __syncthreads();
        scan[tid] += add;
        __syncthreads();
    }
    int excl = beg + scan[tid] - c;
    int node = (b << B2SHIFT) + tid;
    if (node < N) {
        row_ptr[node] = excl;
        dsq[node] = (c > 0) ? rsqrtf((float)c) : 0.0f;
    }
    __syncthreads();
    hist[tid] = excl;               // reuse as per-node cursor
    __syncthreads();
    for (int e = beg + tid; e < end; e += 256) {
        int v = binned[e];
        int pos = atomicAdd(&hist[v & (B2ROWS - 1)], 1);
        csr[pos] = v >> B2SHIFT;
    }
}

// ---------------------------------------------------------------------------
// side pass: one wave per node, lane = component, wave-uniform edge loop.
// Epilogue emits the MFMA A-matrix directly:
//   X[n][0:64]   = bf16(side)            (side = dsq[n]*sum egow[src])
//   X[n][64:128] = bf16(side * ego)
// ---------------------------------------------------------------------------
__global__ __launch_bounds__(256) void k_side(const int* __restrict__ row_ptr,
                                              const int* __restrict__ csr,
                                              const float* __restrict__ dsq,
                                              const unsigned short* __restrict__ egow,
                                              const unsigned short* __restrict__ egob,
                                              unsigned short* __restrict__ X, int N) {
    int wave = threadIdx.x >> 6;
    int lane = threadIdx.x & 63;
    int n = blockIdx.x * 4 + wave;
    if (n >= N) return;
    int beg = __builtin_amdgcn_readfirstlane(row_ptr[n]);
    int end = __builtin_amdgcn_readfirstlane(row_ptr[n + 1]);
    float a0 = 0.f, a1 = 0.f, a2 = 0.f, a3 = 0.f;
    int e = beg;
    for (; e + 8 <= end; e += 8) {
        int s0 = __builtin_amdgcn_readfirstlane(csr[e + 0]);
        int s1 = __builtin_amdgcn_readfirstlane(csr[e + 1]);
        int s2 = __builtin_amdgcn_readfirstlane(csr[e + 2]);
        int s3 = __builtin_amdgcn_readfirstlane(csr[e + 3]);
        int s4 = __builtin_amdgcn_readfirstlane(csr[e + 4]);
        int s5 = __builtin_amdgcn_readfirstlane(csr[e + 5]);
        int s6 = __builtin_amdgcn_readfirstlane(csr[e + 6]);
        int s7 = __builtin_amdgcn_readfirstlane(csr[e + 7]);
        float v0 = b2f(egow[(size_t)s0 * EMB + lane]);
        float v1 = b2f(egow[(size_t)s1 * EMB + lane]);
        float v2 = b2f(egow[(size_t)s2 * EMB + lane]);
        float v3 = b2f(egow[(size_t)s3 * EMB + lane]);
        float v4 = b2f(egow[(size_t)s4 * EMB + lane]);
        float v5 = b2f(egow[(size_t)s5 * EMB + lane]);
        float v6 = b2f(egow[(size_t)s6 * EMB + lane]);
        float v7 = b2f(egow[(size_t)s7 * EMB + lane]);
        a0 += v0 + v4;
        a1 += v1 + v5;
        a2 += v2 + v6;
        a3 += v3 + v7;
    }
    for (; e < end; e++) {
        int s = __builtin_amdgcn_readfirstlane(csr[e]);
        a0 += b2f(egow[(size_t)s * EMB + lane]);
    }
    float s = dsq[n] * ((a0 + a1) + (a2 + a3));
    float eg = b2f(egob[(size_t)n * EMB + lane]);
    X[(size_t)n * 128 + lane] = f2b(s);
    X[(size_t)n * 128 + 64 + lane] = f2b(s * eg);
}

// ---------------------------------------------------------------------------
// MFMA transform: C = X @ [Wgc; Wbi] + b  (K=128, bf16 16x16x32)
// W^T staged in LDS as bf16 (stride 136 shorts: 16B-aligned b128 reads,
// 2-way bank aliasing only). 16 B-fragments in registers; 4 row-tiles/wave.
// Epilogue: leaky-relu, quad-shfl row-norm, write egob/egow/all_eb (bf16).
// ---------------------------------------------------------------------------
__global__ __launch_bounds__(256, 2) void k_mt(
        const unsigned short* __restrict__ X,
        unsigned short* __restrict__ egob, unsigned short* __restrict__ egow,
        const float* __restrict__ dsq,
        const float* __restrict__ Wgc, const float* __restrict__ bgc,
        const float* __restrict__ Wbi, const float* __restrict__ bbi,
        unsigned short* __restrict__ all_eb, int N, int layer_col) {
    __shared__ unsigned short sWT[64 * 136];   // [n][k] bf16, k in [0,128)
    __shared__ float sB[64];
    int tid = threadIdx.x;
    for (int i = tid; i < 64 * 64; i += 256) {
        int k = i >> 6, n = i & 63;
        sWT[n * 136 + k]      = f2b(Wgc[i]);
        sWT[n * 136 + 64 + k] = f2b(Wbi[i]);
    }
    if (tid < 64) sB[tid] = bgc[tid] + bbi[tid];
    __syncthreads();

    int wave = tid >> 6, lane = tid & 63;
    int q = lane >> 4, col = lane & 15;

    v8s Bf[4][4];                               // [nt][kt]
#pragma unroll
    for (int nt = 0; nt < 4; nt++)
#pragma unroll
        for (int kt = 0; kt < 4; kt++)
            Bf[nt][kt] = *(const v8s*)&sWT[(nt * 16 + col) * 136 + kt * 32 + q * 8];

    int nrt = (N + 15) >> 4;
    int rt0 = (blockIdx.x * 4 + wave) * 4;      // 4 row-tiles per wave
    int rt1 = min(rt0 + 4, nrt);
    for (int t = rt0; t < rt1; t++) {
        int r0 = t << 4;
        int rowA = min(r0 + col, N - 1);
        v8s Af[4];
#pragma unroll
        for (int kt = 0; kt < 4; kt++)
            Af[kt] = *(const v8s*)&X[(size_t)rowA * 128 + kt * 32 + q * 8];
        v4f acc[4];
#pragma unroll
        for (int nt = 0; nt < 4; nt++) {
            float b = sB[nt * 16 + col];
            acc[nt] = (v4f){b, b, b, b};
        }
#pragma unroll
        for (int kt = 0; kt < 4; kt++)
#pragma unroll
            for (int nt = 0; nt < 4; nt++)
                acc[nt] = __builtin_amdgcn_mfma_f32_16x16x32_bf16(
                    Af[kt], Bf[nt][kt], acc[nt], 0, 0, 0);
        // epilogue: row = r0 + q*4 + reg, col = nt*16 + (lane&15)
#pragma unroll
        for (int reg = 0; reg < 4; reg++) {
            int row = r0 + q * 4 + reg;
            float v[4];
            float ssq = 0.f;
#pragma unroll
            for (int nt = 0; nt < 4; nt++) {
                float x = acc[nt][reg];
                x = x > 0.f ? x : 0.2f * x;
                v[nt] = x;
                ssq += x * x;
            }
            ssq += __shfl_xor(ssq, 1, 64);
            ssq += __shfl_xor(ssq, 2, 64);
            ssq += __shfl_xor(ssq, 4, 64);
            ssq += __shfl_xor(ssq, 8, 64);
            float inv = 1.0f / fmaxf(sqrtf(ssq), 1e-12f);
            if (row < N) {
                float dn = dsq[row];
#pragma unroll
                for (int nt = 0; nt < 4; nt++) {
                    int c = nt * 16 + col;
                    egob[(size_t)row * EMB + c] = f2b(v[nt]);
                    egow[(size_t)row * EMB + c] = f2b(v[nt] * dn);
                    all_eb[(size_t)row * 256 + layer_col + c] = f2b(v[nt] * inv);
                }
            }
        }
    }
}

// ---------------------------------------------------------------------------
// out(f32) = [all_eb[users], all_eb[nu+pos], all_eb[nu+neg]] (bf16 -> f32)
// ---------------------------------------------------------------------------
__global__ void k_gather(const unsigned short* __restrict__ all_eb,
                         const int* __restrict__ users,
                         const int* __restrict__ pos,
                         const int* __restrict__ neg,
                         float* __restrict__ out, int n_user, int batch) {
    int idx = blockIdx.x * blockDim.x + threadIdx.x;
    int total = batch * 256;
    if (idx >= 3 * total) return;
    int which = idx / total;
    int r = idx - which * total;
    int b = r >> 8;
    int c = r & 255;
    int node;
    if (which == 0) node = users[b];
    else if (which == 1) node = n_user + pos[b];
    else node = n_user + neg[b];
    out[idx] = b2f(all_eb[(size_t)node * 256 + c]);
}

static inline size_t align256(size_t x) { return (x + 255) & ~(size_t)255; }

extern "C" void kernel_launch(void* const* d_in, const int* in_sizes, int n_in,
                              void* d_out, int out_size, void* d_ws, size_t ws_size,
                              hipStream_t stream) {
    const float* user_emb = (const float*)d_in[0];
    const float* item_emb = (const float*)d_in[1];
    const float* W_gc = (const float*)d_in[2];
    const float* b_gc = (const float*)d_in[3];
    const float* W_bi = (const float*)d_in[4];
    const float* b_bi = (const float*)d_in[5];
    const int* edge_src = (const int*)d_in[7];
    const int* edge_dst = (const int*)d_in[8];
    const int* users = (const int*)d_in[9];
    const int* pos = (const int*)d_in[10];
    const int* neg = (const int*)d_in[11];

    int n_user = in_sizes[0] / EMB;
    int n_item = in_sizes[1] / EMB;
    int N = n_user + n_item;
    int M = in_sizes[6];
    int layers = in_sizes[2] / (EMB * EMB);
    int batch = in_sizes[9];
    float* out = (float*)d_out;

    int nb2 = (N + B2ROWS - 1) >> B2SHIFT;       // 586 buckets
    int nrt = (N + 15) >> 4;                     // 16-row tiles

    // workspace carve (~187 MB)
    char* p = (char*)d_ws;
    unsigned short* egob = (unsigned short*)p;   p += align256((size_t)N * EMB * 2);
    unsigned short* egow = (unsigned short*)p;   p += align256((size_t)N * EMB * 2);
    unsigned short* X = (unsigned short*)p;      p += align256((size_t)N * 128 * 2);
    unsigned short* all_eb = (unsigned short*)p; p += align256((size_t)N * 256 * 2);
    float* dsq = (float*)p;            p += align256((size_t)N * 4);
    int* row_ptr = (int*)p;            p += align256((size_t)(N + 1) * 4);
    int* bins = (int*)p;               p += align256((size_t)nb2 * 4);
    int* boff = (int*)p;               p += align256((size_t)(nb2 + 1) * 4);
    int* bcur = (int*)p;               p += align256((size_t)nb2 * 4);
    int* binned = (int*)p;             p += align256((size_t)M * 4);
    int* csr = (int*)p;                p += align256((size_t)M * 4);

    hipMemsetAsync(bins, 0, (size_t)nb2 * 4, stream);   // 2.3 KB

    // bucket-first CSR build (produces row_ptr, dsq, csr)
    k_bhist<<<512, 256, 0, stream>>>(edge_dst, bins, M, nb2);
    k_bscan<<<1, 1024, 0, stream>>>(bins, boff, bcur, row_ptr, nb2, N);
    k_bin<<<512, 256, 0, stream>>>(edge_src, edge_dst, bcur, binned, M, nb2);
    k_csrb<<<nb2, 256, 0, stream>>>(boff, binned, row_ptr, dsq, csr, N);

    // init AFTER csrb (needs dsq for the pre-scaled gather table)
    k_init_ego<<<(N * EMB + 255) / 256, 256, 0, stream>>>(
        user_emb, item_emb, dsq, egob, egow, all_eb, n_user, N);

    for (int k = 0; k < layers; k++) {
        k_side<<<(N + 3) / 4, 256, 0, stream>>>(row_ptr, csr, dsq, egow, egob, X, N);
        k_mt<<<(nrt + 15) / 16, 256, 0, stream>>>(
            X, egob, egow, dsq,
            W_gc + (size_t)k * EMB * EMB, b_gc + (size_t)k * EMB,
            W_bi + (size_t)k * EMB * EMB, b_bi + (size_t)k * EMB,
            all_eb, N, (k + 1) * EMB);
    }

    k_gather<<<(3 * batch * 256 + 255) / 256, 256, 0, stream>>>(
        all_eb, users, pos, neg, out, n_user, batch);
}

// Round 12
// 622.341 us; speedup vs baseline: 9.4718x; 1.0001x over previous
//
#include <hip/hip_runtime.h>

#define EMB 64
#define B2SHIFT 8                 // 256 dst rows per bucket
#define B2ROWS 256
#define MAXB 1024                 // LDS hist capacity (586 buckets actual)

typedef short v8s __attribute__((ext_vector_type(8)));
typedef float v4f __attribute__((ext_vector_type(4)));

__device__ __forceinline__ float b2f(unsigned short u) {
    return __uint_as_float(((unsigned int)u) << 16);
}
__device__ __forceinline__ unsigned short f2b(float f) {
    unsigned int u = __float_as_uint(f);
    u += 0x7FFF + ((u >> 16) & 1);          // round-to-nearest-even
    return (unsigned short)(u >> 16);
}

// ---------------------------------------------------------------------------
// init (runs AFTER csr build so dsq is available):
// egob = bf16(ego); egow = bf16(dsq[n]*ego); all_eb[:,0:64] = bf16(ego)
// ---------------------------------------------------------------------------
__global__ void k_init_ego(const float* __restrict__ user_emb,
                           const float* __restrict__ item_emb,
                           const float* __restrict__ dsq,
                           unsigned short* __restrict__ egob,
                           unsigned short* __restrict__ egow,
                           unsigned short* __restrict__ all_eb,
                           int n_user, int N) {
    int idx = blockIdx.x * blockDim.x + threadIdx.x;
    int total = N * EMB;
    if (idx >= total) return;
    int n = idx >> 6;
    int c = idx & 63;
    float v = (n < n_user) ? user_emb[idx] : item_emb[(size_t)(n - n_user) * EMB + c];
    unsigned short b = f2b(v);
    egob[idx] = b;
    egow[idx] = f2b(dsq[n] * v);
    all_eb[(size_t)n * 256 + c] = b;
}

// ---------------------------------------------------------------------------
// Bucket histogram (586 buckets): LDS pre-aggregation, ~300K global atomics
// ---------------------------------------------------------------------------
__global__ __launch_bounds__(256) void k_bhist(const int* __restrict__ dst,
                                               int* __restrict__ bins,
                                               int M, int nb2) {
    __shared__ int h[MAXB];
    for (int i = threadIdx.x; i < nb2; i += 256) h[i] = 0;
    __syncthreads();
    for (int e = blockIdx.x * 256 + threadIdx.x; e < M; e += gridDim.x * 256)
        atomicAdd(&h[dst[e] >> B2SHIFT], 1);
    __syncthreads();
    for (int i = threadIdx.x; i < nb2; i += 256)
        if (h[i]) atomicAdd(&bins[i], h[i]);
}

// ---------------------------------------------------------------------------
// Exclusive scan of nb2 (<=1024) bins -> boff[0..P], bcur copy; row_ptr[N]=M
// ---------------------------------------------------------------------------
__global__ __launch_bounds__(1024) void k_bscan(const int* __restrict__ bins,
                                                int* __restrict__ boff,
                                                int* __restrict__ bcur,
                                                int* __restrict__ row_ptr,
                                                int P, int N) {
    __shared__ int buf[1024];
    int tid = threadIdx.x;
    int v = (tid < P) ? bins[tid] : 0;
    buf[tid] = v;
    __syncthreads();
    for (int d = 1; d < 1024; d <<= 1) {
        int add = (tid >= d) ? buf[tid - d] : 0;
        __syncthreads();
        buf[tid] += add;
        __syncthreads();
    }
    if (tid < P) {
        int excl = buf[tid] - v;
        boff[tid] = excl;
        bcur[tid] = excl;
    }
    if (tid == P - 1) {
        boff[P] = buf[tid];
        row_ptr[N] = buf[tid];
    }
}

// ---------------------------------------------------------------------------
// Multisplit pass 1: block-private runs per bucket (single-writer lines)
// entry = (src << 8) | (dst & 255)
// ---------------------------------------------------------------------------
__global__ __launch_bounds__(256) void k_bin(const int* __restrict__ src,
                                             const int* __restrict__ dst,
                                             int* __restrict__ bcur,
                                             int* __restrict__ binned,
                                             int M, int nb2) {
    __shared__ int hist[MAXB];
    __shared__ int runcur[MAXB];
    int chunk = (M + gridDim.x - 1) / gridDim.x;
    int lo = blockIdx.x * chunk;
    int hi = min(lo + chunk, M);
    for (int i = threadIdx.x; i < nb2; i += 256) hist[i] = 0;
    __syncthreads();
    for (int e = lo + threadIdx.x; e < hi; e += 256)
        atomicAdd(&hist[dst[e] >> B2SHIFT], 1);
    __syncthreads();
    for (int i = threadIdx.x; i < nb2; i += 256) {
        int c = hist[i];
        runcur[i] = c ? atomicAdd(&bcur[i], c) : 0;
    }
    __syncthreads();
    for (int e = lo + threadIdx.x; e < hi; e += 256) {
        int d = dst[e];
        int pos = atomicAdd(&runcur[d >> B2SHIFT], 1);
        binned[pos] = (src[e] << B2SHIFT) | (d & (B2ROWS - 1));
    }
}

// ---------------------------------------------------------------------------
// Multisplit pass 2 + CSR finalize (also produces row_ptr and dsq)
// ---------------------------------------------------------------------------
__global__ __launch_bounds__(256) void k_csrb(const int* __restrict__ boff,
                                              const int* __restrict__ binned,
                                              int* __restrict__ row_ptr,
                                              float* __restrict__ dsq,
                                              int* __restrict__ csr, int N) {
    __shared__ int hist[B2ROWS];
    __shared__ int scan[B2ROWS];
    int b = blockIdx.x;
    int beg = boff[b], end = boff[b + 1];
    int tid = threadIdx.x;
    hist[tid] = 0;
    __syncthreads();
    for (int e = beg + tid; e < end; e += 256)
        atomicAdd(&hist[binned[e] & (B2ROWS - 1)], 1);
    __syncthreads();
    int c = hist[tid];
    scan[tid] = c;
    __syncthreads();
    for (int d = 1; d < B2ROWS; d <<= 1) {
        int add = (tid >= d) ? scan[tid - d] : 0;
        __syncthreads();
        scan[tid] += add;
        __syncthreads();
    }
    int excl = beg + scan[tid] - c;
    int node = (b << B2SHIFT) + tid;
    if (node < N) {
        row_ptr[node] = excl;
        dsq[node] = (c > 0) ? rsqrtf((float)c) : 0.0f;
    }
    __syncthreads();
    hist[tid] = excl;               // reuse as per-node cursor
    __syncthreads();
    for (int e = beg + tid; e < end; e += 256) {
        int v = binned[e];
        int pos = atomicAdd(&hist[v & (B2ROWS - 1)], 1);
        csr[pos] = v >> B2SHIFT;
    }
}

// ---------------------------------------------------------------------------
// side pass: one wave per node, lane = component. Edge indices are loaded
// 64-at-a-time through lanes (1 vmem per <=64 edges) and extracted with
// v_readlane (SALU) — vmem issues per edge drop to ~1 (the gather itself).
// Epilogue emits the MFMA A-matrix: X[n][0:64]=bf16(side),
// X[n][64:128]=bf16(side*ego)
// ---------------------------------------------------------------------------
__global__ __launch_bounds__(256) void k_side(const int* __restrict__ row_ptr,
                                              const int* __restrict__ csr,
                                              const float* __restrict__ dsq,
                                              const unsigned short* __restrict__ egow,
                                              const unsigned short* __restrict__ egob,
                                              unsigned short* __restrict__ X, int N) {
    int wave = threadIdx.x >> 6;
    int lane = threadIdx.x & 63;
    int n = blockIdx.x * 4 + wave;
    if (n >= N) return;
    int beg = __builtin_amdgcn_readfirstlane(row_ptr[n]);
    int end = __builtin_amdgcn_readfirstlane(row_ptr[n + 1]);
    float a0 = 0.f, a1 = 0.f, a2 = 0.f, a3 = 0.f;
    int e = beg;
    while (e < end) {
        int take = end - e;
        if (take > 64) take = 64;
        int vidx = csr[min(e + lane, end - 1)];   // one vmem for <=64 indices
        int j = 0;
        for (; j + 8 <= take; j += 8) {
            int s0 = __builtin_amdgcn_readlane(vidx, j + 0);
            int s1 = __builtin_amdgcn_readlane(vidx, j + 1);
            int s2 = __builtin_amdgcn_readlane(vidx, j + 2);
            int s3 = __builtin_amdgcn_readlane(vidx, j + 3);
            int s4 = __builtin_amdgcn_readlane(vidx, j + 4);
            int s5 = __builtin_amdgcn_readlane(vidx, j + 5);
            int s6 = __builtin_amdgcn_readlane(vidx, j + 6);
            int s7 = __builtin_amdgcn_readlane(vidx, j + 7);
            float v0 = b2f(egow[(size_t)s0 * EMB + lane]);
            float v1 = b2f(egow[(size_t)s1 * EMB + lane]);
            float v2 = b2f(egow[(size_t)s2 * EMB + lane]);
            float v3 = b2f(egow[(size_t)s3 * EMB + lane]);
            float v4 = b2f(egow[(size_t)s4 * EMB + lane]);
            float v5 = b2f(egow[(size_t)s5 * EMB + lane]);
            float v6 = b2f(egow[(size_t)s6 * EMB + lane]);
            float v7 = b2f(egow[(size_t)s7 * EMB + lane]);
            a0 += v0 + v4;
            a1 += v1 + v5;
            a2 += v2 + v6;
            a3 += v3 + v7;
        }
        for (; j < take; j++) {
            int s = __builtin_amdgcn_readlane(vidx, j);
            a0 += b2f(egow[(size_t)s * EMB + lane]);
        }
        e += take;
    }
    float s = dsq[n] * ((a0 + a1) + (a2 + a3));
    float eg = b2f(egob[(size_t)n * EMB + lane]);
    X[(size_t)n * 128 + lane] = f2b(s);
    X[(size_t)n * 128 + 64 + lane] = f2b(s * eg);
}

// ---------------------------------------------------------------------------
// MFMA transform: C = X @ [Wgc; Wbi] + b  (K=128, bf16 16x16x32)
// W^T staged in LDS as bf16 (stride 136 shorts). 16 B-fragments in regs;
// 4 row-tiles/wave. Epilogue: leaky-relu, quad-shfl row-norm, bf16 stores.
// ---------------------------------------------------------------------------
__global__ __launch_bounds__(256, 2) void k_mt(
        const unsigned short* __restrict__ X,
        unsigned short* __restrict__ egob, unsigned short* __restrict__ egow,
        const float* __restrict__ dsq,
        const float* __restrict__ Wgc, const float* __restrict__ bgc,
        const float* __restrict__ Wbi, const float* __restrict__ bbi,
        unsigned short* __restrict__ all_eb, int N, int layer_col) {
    __shared__ unsigned short sWT[64 * 136];   // [n][k] bf16, k in [0,128)
    __shared__ float sB[64];
    int tid = threadIdx.x;
    for (int i = tid; i < 64 * 64; i += 256) {
        int k = i >> 6, n = i & 63;
        sWT[n * 136 + k]      = f2b(Wgc[i]);
        sWT[n * 136 + 64 + k] = f2b(Wbi[i]);
    }
    if (tid < 64) sB[tid] = bgc[tid] + bbi[tid];
    __syncthreads();

    int wave = tid >> 6, lane = tid & 63;
    int q = lane >> 4, col = lane & 15;

    v8s Bf[4][4];                               // [nt][kt]
#pragma unroll
    for (int nt = 0; nt < 4; nt++)
#pragma unroll
        for (int kt = 0; kt < 4; kt++)
            Bf[nt][kt] = *(const v8s*)&sWT[(nt * 16 + col) * 136 + kt * 32 + q * 8];

    int nrt = (N + 15) >> 4;
    int rt0 = (blockIdx.x * 4 + wave) * 4;      // 4 row-tiles per wave
    int rt1 = min(rt0 + 4, nrt);
    for (int t = rt0; t < rt1; t++) {
        int r0 = t << 4;
        int rowA = min(r0 + col, N - 1);
        v8s Af[4];
#pragma unroll
        for (int kt = 0; kt < 4; kt++)
            Af[kt] = *(const v8s*)&X[(size_t)rowA * 128 + kt * 32 + q * 8];
        v4f acc[4];
#pragma unroll
        for (int nt = 0; nt < 4; nt++) {
            float b = sB[nt * 16 + col];
            acc[nt] = (v4f){b, b, b, b};
        }
#pragma unroll
        for (int kt = 0; kt < 4; kt++)
#pragma unroll
            for (int nt = 0; nt < 4; nt++)
                acc[nt] = __builtin_amdgcn_mfma_f32_16x16x32_bf16(
                    Af[kt], Bf[nt][kt], acc[nt], 0, 0, 0);
        // epilogue: row = r0 + q*4 + reg, col = nt*16 + (lane&15)
#pragma unroll
        for (int reg = 0; reg < 4; reg++) {
            int row = r0 + q * 4 + reg;
            float v[4];
            float ssq = 0.f;
#pragma unroll
            for (int nt = 0; nt < 4; nt++) {
                float x = acc[nt][reg];
                x = x > 0.f ? x : 0.2f * x;
                v[nt] = x;
                ssq += x * x;
            }
            ssq += __shfl_xor(ssq, 1, 64);
            ssq += __shfl_xor(ssq, 2, 64);
            ssq += __shfl_xor(ssq, 4, 64);
            ssq += __shfl_xor(ssq, 8, 64);
            float inv = 1.0f / fmaxf(sqrtf(ssq), 1e-12f);
            if (row < N) {
                float dn = dsq[row];
#pragma unroll
                for (int nt = 0; nt < 4; nt++) {
                    int c = nt * 16 + col;
                    egob[(size_t)row * EMB + c] = f2b(v[nt]);
                    egow[(size_t)row * EMB + c] = f2b(v[nt] * dn);
                    all_eb[(size_t)row * 256 + layer_col + c] = f2b(v[nt] * inv);
                }
            }
        }
    }
}

// ---------------------------------------------------------------------------
// out(f32) = [all_eb[users], all_eb[nu+pos], all_eb[nu+neg]] (bf16 -> f32)
// ---------------------------------------------------------------------------
__global__ void k_gather(const unsigned short* __restrict__ all_eb,
                         const int* __restrict__ users,
                         const int* __restrict__ pos,
                         const int* __restrict__ neg,
                         float* __restrict__ out, int n_user, int batch) {
    int idx = blockIdx.x * blockDim.x + threadIdx.x;
    int total = batch * 256;
    if (idx >= 3 * total) return;
    int which = idx / total;
    int r = idx - which * total;
    int b = r >> 8;
    int c = r & 255;
    int node;
    if (which == 0) node = users[b];
    else if (which == 1) node = n_user + pos[b];
    else node = n_user + neg[b];
    out[idx] = b2f(all_eb[(size_t)node * 256 + c]);
}

static inline size_t align256(size_t x) { return (x + 255) & ~(size_t)255; }

extern "C" void kernel_launch(void* const* d_in, const int* in_sizes, int n_in,
                              void* d_out, int out_size, void* d_ws, size_t ws_size,
                              hipStream_t stream) {
    const float* user_emb = (const float*)d_in[0];
    const float* item_emb = (const float*)d_in[1];
    const float* W_gc = (const float*)d_in[2];
    const float* b_gc = (const float*)d_in[3];
    const float* W_bi = (const float*)d_in[4];
    const float* b_bi = (const float*)d_in[5];
    const int* edge_src = (const int*)d_in[7];
    const int* edge_dst = (const int*)d_in[8];
    const int* users = (const int*)d_in[9];
    const int* pos = (const int*)d_in[10];
    const int* neg = (const int*)d_in[11];

    int n_user = in_sizes[0] / EMB;
    int n_item = in_sizes[1] / EMB;
    int N = n_user + n_item;
    int M = in_sizes[6];
    int layers = in_sizes[2] / (EMB * EMB);
    int batch = in_sizes[9];
    float* out = (float*)d_out;

    int nb2 = (N + B2ROWS - 1) >> B2SHIFT;       // 586 buckets
    int nrt = (N + 15) >> 4;                     // 16-row tiles

    // workspace carve (~187 MB)
    char* p = (char*)d_ws;
    unsigned short* egob = (unsigned short*)p;   p += align256((size_t)N * EMB * 2);
    unsigned short* egow = (unsigned short*)p;   p += align256((size_t)N * EMB * 2);
    unsigned short* X = (unsigned short*)p;      p += align256((size_t)N * 128 * 2);
    unsigned short* all_eb = (unsigned short*)p; p += align256((size_t)N * 256 * 2);
    float* dsq = (float*)p;            p += align256((size_t)N * 4);
    int* row_ptr = (int*)p;            p += align256((size_t)(N + 1) * 4);
    int* bins = (int*)p;               p += align256((size_t)nb2 * 4);
    int* boff = (int*)p;               p += align256((size_t)(nb2 + 1) * 4);
    int* bcur = (int*)p;               p += align256((size_t)nb2 * 4);
    int* binned = (int*)p;             p += align256((size_t)M * 4);
    int* csr = (int*)p;                p += align256((size_t)M * 4);

    hipMemsetAsync(bins, 0, (size_t)nb2 * 4, stream);   // 2.3 KB

    // bucket-first CSR build (produces row_ptr, dsq, csr)
    k_bhist<<<512, 256, 0, stream>>>(edge_dst, bins, M, nb2);
    k_bscan<<<1, 1024, 0, stream>>>(bins, boff, bcur, row_ptr, nb2, N);
    k_bin<<<512, 256, 0, stream>>>(edge_src, edge_dst, bcur, binned, M, nb2);
    k_csrb<<<nb2, 256, 0, stream>>>(boff, binned, row_ptr, dsq, csr, N);

    // init AFTER csrb (needs dsq for the pre-scaled gather table)
    k_init_ego<<<(N * EMB + 255) / 256, 256, 0, stream>>>(
        user_emb, item_emb, dsq, egob, egow, all_eb, n_user, N);

    for (int k = 0; k < layers; k++) {
        k_side<<<(N + 3) / 4, 256, 0, stream>>>(row_ptr, csr, dsq, egow, egob, X, N);
        k_mt<<<(nrt + 15) / 16, 256, 0, stream>>>(
            X, egob, egow, dsq,
            W_gc + (size_t)k * EMB * EMB, b_gc + (size_t)k * EMB,
            W_bi + (size_t)k * EMB * EMB, b_bi + (size_t)k * EMB,
            all_eb, N, (k + 1) * EMB);
    }

    k_gather<<<(3 * batch * 256 + 255) / 256, 256, 0, stream>>>(
        all_eb, users, pos, neg, out, n_user, batch);
}